// Round 4
// baseline (579.702 us; speedup 1.0000x reference)
//
#include <hip/hip_runtime.h>

typedef __bf16 bf16_t;
typedef bf16_t bf16x8 __attribute__((ext_vector_type(8)));
typedef float f32x4 __attribute__((ext_vector_type(4)));
typedef float f32x8 __attribute__((ext_vector_type(8)));

#define B_N 4
#define S_N 1024
#define E_N 1024
#define H_N 16
#define D_N 64

static __device__ __forceinline__ float b2f(bf16_t x) { return (float)x; }
static __device__ __forceinline__ bf16_t f2b(float x) { return (bf16_t)x; }

// load 8 contiguous elements as bf16x8 (converting if source is fp32)
static __device__ __forceinline__ bf16x8 load8_bf16(const float* p) {
  f32x8 v = *(const f32x8*)p;
  bf16x8 r;
#pragma unroll
  for (int i = 0; i < 8; ++i) r[i] = f2b(v[i]);
  return r;
}
static __device__ __forceinline__ bf16x8 load8_bf16(const bf16_t* p) {
  return *(const bf16x8*)p;
}

// ---------------------------------------------------------------------------
// Projection GEMM: C[m,n] = sum_k A[m,k] * W[n,k] + bias[n]
// A: (4096,1024) row-major (k contiguous), W: (1024,1024) fp32 (n,k).
// mode 0: C -> (B,H,S,D) bf16   (Q or K)
// mode 2: C -> (B,H,D,S) bf16   (V transposed)
// mode 3: C -> flat (4096,1024) FP32 (final out)
// 128x128 tile, BK=32, 4 waves (2x2), each wave 4x4 frags of 16x16x32.
// ---------------------------------------------------------------------------
template <typename AT>
__global__ __launch_bounds__(256) void proj_gemm(
    const AT* __restrict__ A, const float* __restrict__ W,
    const float* __restrict__ bias,
    bf16_t* __restrict__ oQ, bf16_t* __restrict__ oVt, float* __restrict__ oF,
    int mode)
{
  constexpr int LDT = 40;               // 32 + 8 pad: breaks bank conflicts
  __shared__ bf16_t As[128 * LDT];
  __shared__ bf16_t Bs[128 * LDT];
  const int tid = threadIdx.x;
  const int m0 = blockIdx.y * 128, n0 = blockIdx.x * 128;
  const int lane = tid & 63, wid = tid >> 6;
  const int wr = wid >> 1, wc = wid & 1;
  const int lr = lane & 15, lh = lane >> 4;
  f32x4 acc[4][4] = {};
  for (int k0 = 0; k0 < 1024; k0 += 32) {
#pragma unroll
    for (int i = 0; i < 2; ++i) {       // stage 128x32 of A and of W
      int f = tid + i * 256;
      int r = f >> 2, c = (f & 3) * 8;
      *(bf16x8*)&As[r * LDT + c] = load8_bf16(&A[(size_t)(m0 + r) * 1024 + k0 + c]);
      *(bf16x8*)&Bs[r * LDT + c] = load8_bf16(&W[(size_t)(n0 + r) * 1024 + k0 + c]);
    }
    __syncthreads();
    bf16x8 af[4], bw[4];
#pragma unroll
    for (int m = 0; m < 4; ++m)
      af[m] = *(const bf16x8*)&As[(wr * 64 + m * 16 + lr) * LDT + lh * 8];
#pragma unroll
    for (int n = 0; n < 4; ++n)
      bw[n] = *(const bf16x8*)&Bs[(wc * 64 + n * 16 + lr) * LDT + lh * 8];
#pragma unroll
    for (int m = 0; m < 4; ++m)
#pragma unroll
      for (int n = 0; n < 4; ++n)
        acc[m][n] = __builtin_amdgcn_mfma_f32_16x16x32_bf16(af[m], bw[n], acc[m][n], 0, 0, 0);
    __syncthreads();
  }
  // epilogue: C/D frag mapping col=lane&15, row=(lane>>4)*4+r  [m89-verified]
#pragma unroll
  for (int n = 0; n < 4; ++n) {
    const int col = n0 + wc * 64 + n * 16 + lr;
    const float bv = bias[col];
    const int h = col >> 6, d = col & 63;
#pragma unroll
    for (int m = 0; m < 4; ++m) {
      const int row0 = m0 + wr * 64 + m * 16 + lh * 4;
#pragma unroll
      for (int r = 0; r < 4; ++r) {
        const int row = row0 + r;                  // token index b*S + s
        const float v = acc[m][n][r] + bv;
        const int b = row >> 10, s = row & 1023;
        if (mode == 0)
          oQ[((size_t)(b * H_N + h) * S_N + s) * D_N + d] = f2b(v);
        else if (mode == 2)
          oVt[((size_t)(b * H_N + h) * D_N + d) * S_N + s] = f2b(v);
        else
          oF[(size_t)row * E_N + col] = v;         // fp32 final output
      }
    }
  }
}

// ---------------------------------------------------------------------------
// scores[bh,q,k] = (Q . K)/8 + rel_bias[h, clip(k-q,-8,8)+8], mask -> -inf
// Per block: 128q x 128k tile, K-contraction = D = 64 (2 MFMA k-steps).
// Output fp32 (harness-visible output #2).
// ---------------------------------------------------------------------------
__global__ __launch_bounds__(256) void scores_kernel(
    const bf16_t* __restrict__ Q, const bf16_t* __restrict__ K,
    const unsigned char* __restrict__ mask, const float* __restrict__ rel_bias,
    float* __restrict__ scores)
{
  const int bh = blockIdx.z, b = bh >> 4, h = bh & 15;
  const int q0 = blockIdx.y * 128, kc0 = blockIdx.x * 128;
  const bf16_t* Qh = Q + (size_t)bh * (S_N * D_N);
  const bf16_t* Kh = K + (size_t)bh * (S_N * D_N);
  const int lane = threadIdx.x & 63, wid = threadIdx.x >> 6;
  const int wr = wid >> 1, wc = wid & 1, lr = lane & 15, lh = lane >> 4;
  f32x4 acc[4][4] = {};
  bf16x8 qa[4][2], kb[4][2];
#pragma unroll
  for (int m = 0; m < 4; ++m)
#pragma unroll
    for (int kk = 0; kk < 2; ++kk)
      qa[m][kk] = *(const bf16x8*)&Qh[(size_t)(q0 + wr * 64 + m * 16 + lr) * D_N + kk * 32 + lh * 8];
#pragma unroll
  for (int n = 0; n < 4; ++n)
#pragma unroll
    for (int kk = 0; kk < 2; ++kk)
      kb[n][kk] = *(const bf16x8*)&Kh[(size_t)(kc0 + wc * 64 + n * 16 + lr) * D_N + kk * 32 + lh * 8];
#pragma unroll
  for (int kk = 0; kk < 2; ++kk)
#pragma unroll
    for (int m = 0; m < 4; ++m)
#pragma unroll
      for (int n = 0; n < 4; ++n)
        acc[m][n] = __builtin_amdgcn_mfma_f32_16x16x32_bf16(qa[m][kk], kb[n][kk], acc[m][n], 0, 0, 0);
  const float neg_inf = -__builtin_inff();
#pragma unroll
  for (int n = 0; n < 4; ++n) {
    const int kcol = kc0 + wc * 64 + n * 16 + lr;
#pragma unroll
    for (int m = 0; m < 4; ++m) {
      const int qrow0 = q0 + wr * 64 + m * 16 + lh * 4;
#pragma unroll
      for (int r = 0; r < 4; ++r) {
        const int qrow = qrow0 + r;
        int rel = kcol - qrow;
        rel = rel < -8 ? -8 : (rel > 8 ? 8 : rel);
        float v = acc[m][n][r] * 0.125f + rel_bias[h * 17 + rel + 8];
        if (mask[(size_t)b * ((size_t)S_N * S_N) + (size_t)qrow * S_N + kcol]) v = neg_inf;
        scores[((size_t)bh * S_N + qrow) * S_N + kcol] = v;
      }
    }
  }
}

// ---------------------------------------------------------------------------
// Row softmax: one wave per 1024-elem row, all fp32.
// ---------------------------------------------------------------------------
__global__ __launch_bounds__(256) void softmax_kernel(
    const float* __restrict__ scores, float* __restrict__ attn)
{
  const int row = blockIdx.x * 4 + (threadIdx.x >> 6);
  const int lane = threadIdx.x & 63;
  const float* src = scores + (size_t)row * 1024;
  f32x8 v0 = *(const f32x8*)&src[lane * 8];
  f32x8 v1 = *(const f32x8*)&src[512 + lane * 8];
  float f[16];
#pragma unroll
  for (int i = 0; i < 8; ++i) { f[i] = v0[i]; f[8 + i] = v1[i]; }
  float m = f[0];
#pragma unroll
  for (int i = 1; i < 16; ++i) m = fmaxf(m, f[i]);
#pragma unroll
  for (int off = 32; off; off >>= 1) m = fmaxf(m, __shfl_xor(m, off));
  float s = 0.f;
#pragma unroll
  for (int i = 0; i < 16; ++i) { f[i] = __expf(f[i] - m); s += f[i]; }
#pragma unroll
  for (int off = 32; off; off >>= 1) s += __shfl_xor(s, off);
  const float inv = 1.0f / s;
  f32x8 o0, o1;
#pragma unroll
  for (int i = 0; i < 8; ++i) { o0[i] = f[i] * inv; o1[i] = f[8 + i] * inv; }
  float* dst = attn + (size_t)row * 1024;
  *(f32x8*)&dst[lane * 8] = o0;
  *(f32x8*)&dst[512 + lane * 8] = o1;
}

// ---------------------------------------------------------------------------
// ctx[bh,q,d] = sum_k attn[bh,q,k] * V[bh,k,d];  V stored transposed (B,H,D,S).
// attn read as fp32 (converted to bf16 fragments on load).
// Block: 256q x 64d, 4 waves stacked on q, K-loop over 1024 in steps of 32.
// Output ctx stored (B,S,E) bf16 with e = h*64+d (ready for out-projection).
// ---------------------------------------------------------------------------
__global__ __launch_bounds__(256) void pv_kernel(
    const float* __restrict__ attn, const bf16_t* __restrict__ Vt,
    bf16_t* __restrict__ ctx)
{
  const int bh = blockIdx.y, b = bh >> 4, h = bh & 15;
  const int q0 = blockIdx.x * 256;
  const int lane = threadIdx.x & 63, wid = threadIdx.x >> 6;
  const int lr = lane & 15, lh = lane >> 4;
  const float* Ph = attn + (size_t)bh * ((size_t)S_N * S_N);
  const bf16_t* Vh = Vt + (size_t)bh * (D_N * S_N);
  f32x4 acc[4][4] = {};
  for (int k0 = 0; k0 < 1024; k0 += 32) {
    bf16x8 pa[4], vb[4];
#pragma unroll
    for (int m = 0; m < 4; ++m)
      pa[m] = load8_bf16(&Ph[(size_t)(q0 + wid * 64 + m * 16 + lr) * S_N + k0 + lh * 8]);
#pragma unroll
    for (int n = 0; n < 4; ++n)
      vb[n] = *(const bf16x8*)&Vh[(size_t)(n * 16 + lr) * S_N + k0 + lh * 8];
#pragma unroll
    for (int m = 0; m < 4; ++m)
#pragma unroll
      for (int n = 0; n < 4; ++n)
        acc[m][n] = __builtin_amdgcn_mfma_f32_16x16x32_bf16(pa[m], vb[n], acc[m][n], 0, 0, 0);
  }
#pragma unroll
  for (int n = 0; n < 4; ++n) {
    const int d = n * 16 + lr;
#pragma unroll
    for (int m = 0; m < 4; ++m) {
      const int qr0 = q0 + wid * 64 + m * 16 + lh * 4;
#pragma unroll
      for (int r = 0; r < 4; ++r) {
        const int q = qr0 + r;
        ctx[((size_t)(b * S_N + q)) * E_N + h * 64 + d] = f2b(acc[m][n][r]);
      }
    }
  }
}

// ---------------------------------------------------------------------------
// d_out is FP32: out (4M) | attn (64M) | scores (64M) floats.
// Scratch liveness plan:
//   Qbf, Kbf (bf16, 8MB each) -> attn fp32 region (256MB; dead once softmax
//                                overwrites attn, stream-ordered)
//   Vtbf (bf16, 8MB)          -> out fp32 region (16MB; dead before the final
//                                out-projection fully overwrites out)
//   CTX (bf16, 8MB)           -> d_ws
// ---------------------------------------------------------------------------
extern "C" void kernel_launch(void* const* d_in, const int* in_sizes, int n_in,
                              void* d_out, int out_size, void* d_ws, size_t ws_size,
                              hipStream_t stream) {
  (void)in_sizes; (void)n_in; (void)out_size; (void)ws_size;
  const float* query = (const float*)d_in[0];
  const float* key   = (const float*)d_in[1];
  const float* value = (const float*)d_in[2];
  const unsigned char* mask = (const unsigned char*)d_in[3];
  const float* Wq = (const float*)d_in[4];
  const float* bq = (const float*)d_in[5];
  const float* Wk = (const float*)d_in[6];
  const float* bk = (const float*)d_in[7];
  const float* Wv = (const float*)d_in[8];
  const float* bv = (const float*)d_in[9];
  const float* Wo = (const float*)d_in[10];
  const float* bo = (const float*)d_in[11];
  const float* rel_bias = (const float*)d_in[12];

  float* out_f    = (float*)d_out;                     //  4,194,304 floats
  float* attn_f   = out_f + (size_t)4194304;           // 67,108,864 floats
  float* scores_f = attn_f + (size_t)67108864;         // 67,108,864 floats

  bf16_t* Qbf  = (bf16_t*)attn_f;                      // 8MB scratch in attn region
  bf16_t* Kbf  = (bf16_t*)attn_f + (size_t)4194304;    // next 8MB
  bf16_t* Vtbf = (bf16_t*)out_f;                       // 8MB scratch in out region
  bf16_t* CTX  = (bf16_t*)d_ws;                        // 8MB of ws

  dim3 blk(256);
  dim3 gproj(8, 32);                                   // (n-tiles, m-tiles)
  proj_gemm<float><<<gproj, blk, 0, stream>>>(query, Wq, bq, Qbf, nullptr, nullptr, 0);
  proj_gemm<float><<<gproj, blk, 0, stream>>>(key,   Wk, bk, Kbf, nullptr, nullptr, 0);
  proj_gemm<float><<<gproj, blk, 0, stream>>>(value, Wv, bv, nullptr, Vtbf, nullptr, 2);
  scores_kernel<<<dim3(8, 8, 64), blk, 0, stream>>>(Qbf, Kbf, mask, rel_bias, scores_f);
  softmax_kernel<<<dim3(16384), blk, 0, stream>>>(scores_f, attn_f);
  pv_kernel<<<dim3(4, 64), blk, 0, stream>>>(attn_f, Vtbf, CTX);
  proj_gemm<bf16_t><<<gproj, blk, 0, stream>>>(CTX, Wo, bo, nullptr, nullptr, out_f, 3);
}

// Round 5
// 518.471 us; speedup vs baseline: 1.1181x; 1.1181x over previous
//
#include <hip/hip_runtime.h>

typedef __bf16 bf16_t;
typedef bf16_t bf16x8 __attribute__((ext_vector_type(8)));
typedef float f32x4 __attribute__((ext_vector_type(4)));
typedef float f32x8 __attribute__((ext_vector_type(8)));

#define B_N 4
#define S_N 1024
#define E_N 1024
#define H_N 16
#define D_N 64

static __device__ __forceinline__ bf16_t f2b(float x) { return (bf16_t)x; }

// ---------------------------------------------------------------------------
// One-shot fp32 -> bf16 conversion of q,k,v (4096x1024 each) and the four
// weight matrices (1024x1024 each). Total 3*2^22 + 4*2^20 = 2^24 elements.
// ---------------------------------------------------------------------------
__global__ __launch_bounds__(256) void convert_kernel(
    const float* __restrict__ q, const float* __restrict__ k, const float* __restrict__ v,
    const float* __restrict__ wq, const float* __restrict__ wk,
    const float* __restrict__ wv, const float* __restrict__ wo,
    bf16_t* __restrict__ dq, bf16_t* __restrict__ dk, bf16_t* __restrict__ dv,
    bf16_t* __restrict__ dwq, bf16_t* __restrict__ dwk,
    bf16_t* __restrict__ dwv, bf16_t* __restrict__ dwo)
{
  const size_t e = ((size_t)blockIdx.x * 256 + threadIdx.x) * 8;
  const float* src; bf16_t* dst; size_t off;
  if (e < 12582912ull) {                       // q | k | v (4M elems each)
    const int which = (int)(e >> 22);
    off = e & 4194303ull;
    src = which == 0 ? q : (which == 1 ? k : v);
    dst = which == 0 ? dq : (which == 1 ? dk : dv);
  } else {                                     // Wq | Wk | Wv | Wo (1M each)
    const size_t e2 = e - 12582912ull;
    const int which = (int)(e2 >> 20);
    off = e2 & 1048575ull;
    src = which == 0 ? wq : (which == 1 ? wk : (which == 2 ? wv : wo));
    dst = which == 0 ? dwq : (which == 1 ? dwk : (which == 2 ? dwv : dwo));
  }
  f32x8 x = *(const f32x8*)(src + off);
  bf16x8 r;
#pragma unroll
  for (int i = 0; i < 8; ++i) r[i] = f2b(x[i]);
  *(bf16x8*)(dst + off) = r;
}

// ---------------------------------------------------------------------------
// Projection GEMM (all-bf16 operands): C[m,n] = sum_k A[m,k]*W[n,k] + bias[n]
// mode 0: C -> (B,H,S,D) bf16 ; mode 2: C -> (B,H,D,S) bf16 (V transposed)
// mode 3: C -> flat (4096,1024) fp32 (final out)
// 128x128 tile, BK=32, 4 waves (2x2), 4x4 frags of 16x16x32 each.
// ---------------------------------------------------------------------------
__global__ __launch_bounds__(256) void proj_gemm(
    const bf16_t* __restrict__ A, const bf16_t* __restrict__ W,
    const float* __restrict__ bias,
    bf16_t* __restrict__ oQ, bf16_t* __restrict__ oVt, float* __restrict__ oF,
    int mode)
{
  constexpr int LDT = 40;               // 32 + 8 pad: breaks bank conflicts
  __shared__ bf16_t As[128 * LDT];
  __shared__ bf16_t Bs[128 * LDT];
  const int tid = threadIdx.x;
  const int m0 = blockIdx.y * 128, n0 = blockIdx.x * 128;
  const int lane = tid & 63, wid = tid >> 6;
  const int wr = wid >> 1, wc = wid & 1;
  const int lr = lane & 15, lh = lane >> 4;
  f32x4 acc[4][4] = {};
  for (int k0 = 0; k0 < 1024; k0 += 32) {
#pragma unroll
    for (int i = 0; i < 2; ++i) {       // stage 128x32 of A and of W
      int f = tid + i * 256;
      int r = f >> 2, c = (f & 3) * 8;
      *(bf16x8*)&As[r * LDT + c] = *(const bf16x8*)&A[(size_t)(m0 + r) * 1024 + k0 + c];
      *(bf16x8*)&Bs[r * LDT + c] = *(const bf16x8*)&W[(size_t)(n0 + r) * 1024 + k0 + c];
    }
    __syncthreads();
    bf16x8 af[4], bw[4];
#pragma unroll
    for (int m = 0; m < 4; ++m)
      af[m] = *(const bf16x8*)&As[(wr * 64 + m * 16 + lr) * LDT + lh * 8];
#pragma unroll
    for (int n = 0; n < 4; ++n)
      bw[n] = *(const bf16x8*)&Bs[(wc * 64 + n * 16 + lr) * LDT + lh * 8];
#pragma unroll
    for (int m = 0; m < 4; ++m)
#pragma unroll
      for (int n = 0; n < 4; ++n)
        acc[m][n] = __builtin_amdgcn_mfma_f32_16x16x32_bf16(af[m], bw[n], acc[m][n], 0, 0, 0);
    __syncthreads();
  }
#pragma unroll
  for (int n = 0; n < 4; ++n) {
    const int col = n0 + wc * 64 + n * 16 + lr;
    const float bv = bias[col];
    const int h = col >> 6, d = col & 63;
#pragma unroll
    for (int m = 0; m < 4; ++m) {
      const int row0 = m0 + wr * 64 + m * 16 + lh * 4;
#pragma unroll
      for (int r = 0; r < 4; ++r) {
        const int row = row0 + r;                  // token index b*S + s
        const float v = acc[m][n][r] + bv;
        const int b = row >> 10, s = row & 1023;
        if (mode == 0)
          oQ[((size_t)(b * H_N + h) * S_N + s) * D_N + d] = f2b(v);
        else if (mode == 2)
          oVt[((size_t)(b * H_N + h) * D_N + d) * S_N + s] = f2b(v);
        else
          oF[(size_t)row * E_N + col] = v;         // fp32 final output
      }
    }
  }
}

// ---------------------------------------------------------------------------
// Fused attention: scores + softmax + PV in one kernel.
// Block = (q-tile of 64 rows, one bh). 4 waves; wave w owns q-rows
// [q0+16w, q0+16w+16) exclusively -> softmax stats are wave-local.
// Pass 1: QK^T + scale + rel_bias + mask -> write scores fp32; row-max in regs.
// Pass 2: re-read scores (L2-hot), accumulate row-sum of exp(s-m).
// Pass 3: re-read scores, p = exp(s-m)/sum -> write attn fp32 AND use p as
//         bf16 A-fragments for PV MFMA against Vt (B,H,D,S). ctx -> (B,S,E).
// ---------------------------------------------------------------------------
__global__ __launch_bounds__(256) void fused_attn(
    const bf16_t* __restrict__ Q, const bf16_t* __restrict__ K,
    const bf16_t* __restrict__ Vt,
    const unsigned char* __restrict__ mask, const float* __restrict__ rel_bias,
    float* __restrict__ scores, float* __restrict__ attn, bf16_t* __restrict__ ctx)
{
  const int bh = blockIdx.y, b = bh >> 4, h = bh & 15;
  const int q0 = blockIdx.x * 64;
  const int lane = threadIdx.x & 63, w = threadIdx.x >> 6;
  const int lr = lane & 15, lh = lane >> 4;
  __shared__ float rowm[64];

  const bf16_t* Qh = Q + (size_t)bh * (S_N * D_N);
  const bf16_t* Kh = K + (size_t)bh * (S_N * D_N);
  const bf16_t* Vh = Vt + (size_t)bh * (D_N * S_N);
  float* Sh = scores + (size_t)bh * S_N * S_N;
  float* Ah = attn + (size_t)bh * S_N * S_N;

  const int qrow_a = q0 + w * 16 + lr;        // A-layout row (pass 2/3)
  const float NEG = -__builtin_inff();

  // Q fragments, held in registers for the whole kernel (16 rows x 64 d)
  bf16x8 qa[2];
  qa[0] = *(const bf16x8*)&Qh[(size_t)qrow_a * D_N + lh * 8];
  qa[1] = *(const bf16x8*)&Qh[(size_t)qrow_a * D_N + 32 + lh * 8];

  // ---- Pass 1: scores + row max -------------------------------------------
  float mymax[4] = {NEG, NEG, NEG, NEG};       // rows q0 + 16w + 4*lh + r
  for (int kt = 0; kt < 8; ++kt) {
    const int kc0 = kt * 128;
    f32x4 acc[8] = {};
#pragma unroll
    for (int n = 0; n < 8; ++n) {
      bf16x8 kb0 = *(const bf16x8*)&Kh[(size_t)(kc0 + n * 16 + lr) * D_N + lh * 8];
      bf16x8 kb1 = *(const bf16x8*)&Kh[(size_t)(kc0 + n * 16 + lr) * D_N + 32 + lh * 8];
      acc[n] = __builtin_amdgcn_mfma_f32_16x16x32_bf16(qa[0], kb0, acc[n], 0, 0, 0);
      acc[n] = __builtin_amdgcn_mfma_f32_16x16x32_bf16(qa[1], kb1, acc[n], 0, 0, 0);
    }
#pragma unroll
    for (int n = 0; n < 8; ++n) {
      const int kcol = kc0 + n * 16 + lr;
#pragma unroll
      for (int r = 0; r < 4; ++r) {
        const int qrow = q0 + w * 16 + lh * 4 + r;
        int rel = kcol - qrow;
        rel = rel < -8 ? -8 : (rel > 8 ? 8 : rel);
        float v = acc[n][r] * 0.125f + rel_bias[h * 17 + rel + 8];
        if (mask[(size_t)b * ((size_t)S_N * S_N) + (size_t)qrow * S_N + kcol]) v = NEG;
        Sh[(size_t)qrow * S_N + kcol] = v;
        mymax[r] = fmaxf(mymax[r], v);
      }
    }
  }
  // reduce row max across the 16 lr lanes (per lh group)
#pragma unroll
  for (int r = 0; r < 4; ++r) {
#pragma unroll
    for (int off = 1; off <= 8; off <<= 1)
      mymax[r] = fmaxf(mymax[r], __shfl_xor(mymax[r], off));
  }
  if (lr == 0) {
#pragma unroll
    for (int r = 0; r < 4; ++r) rowm[w * 16 + lh * 4 + r] = mymax[r];
  }
  __syncthreads();
  const float mrow = rowm[w * 16 + lr];        // max for row qrow_a

  // ---- Pass 2: row sum (scores re-read is L2-hot: 256KB/block) ------------
  float mysum = 0.f;
  for (int kt = 0; kt < 32; ++kt) {
    f32x8 s = *(const f32x8*)&Sh[(size_t)qrow_a * S_N + kt * 32 + lh * 8];
#pragma unroll
    for (int j = 0; j < 8; ++j) mysum += __expf(s[j] - mrow);
  }
  mysum += __shfl_xor(mysum, 16);
  mysum += __shfl_xor(mysum, 32);
  const float invs = 1.0f / mysum;

  // ---- Pass 3: attn write + PV accumulate ---------------------------------
  f32x4 accp[4] = {};
  for (int kt = 0; kt < 32; ++kt) {
    f32x8 s = *(const f32x8*)&Sh[(size_t)qrow_a * S_N + kt * 32 + lh * 8];
    f32x8 pn; bf16x8 pa;
#pragma unroll
    for (int j = 0; j < 8; ++j) {
      float p = __expf(s[j] - mrow) * invs;
      pn[j] = p;
      pa[j] = f2b(p);
    }
    *(f32x8*)&Ah[(size_t)qrow_a * S_N + kt * 32 + lh * 8] = pn;
#pragma unroll
    for (int n = 0; n < 4; ++n) {
      bf16x8 vb = *(const bf16x8*)&Vh[(size_t)(n * 16 + lr) * S_N + kt * 32 + lh * 8];
      accp[n] = __builtin_amdgcn_mfma_f32_16x16x32_bf16(pa, vb, accp[n], 0, 0, 0);
    }
  }
  // ctx epilogue: (B,S,E), e = h*64 + d
#pragma unroll
  for (int n = 0; n < 4; ++n) {
    const int d = n * 16 + lr;
#pragma unroll
    for (int r = 0; r < 4; ++r) {
      const int qrow = q0 + w * 16 + lh * 4 + r;
      ctx[((size_t)(b * S_N + qrow)) * E_N + h * 64 + d] = f2b(accp[n][r]);
    }
  }
}

// ---------------------------------------------------------------------------
// d_out (fp32): out (4M) | attn (64M) | scores (64M).
// d_ws (~2GiB confirmed by poison-fill WRITE_SIZE): 64MB used, layout below.
// ---------------------------------------------------------------------------
extern "C" void kernel_launch(void* const* d_in, const int* in_sizes, int n_in,
                              void* d_out, int out_size, void* d_ws, size_t ws_size,
                              hipStream_t stream) {
  (void)in_sizes; (void)n_in; (void)out_size; (void)ws_size;
  const float* query = (const float*)d_in[0];
  const float* key   = (const float*)d_in[1];
  const float* value = (const float*)d_in[2];
  const unsigned char* mask = (const unsigned char*)d_in[3];
  const float* Wq = (const float*)d_in[4];
  const float* bq = (const float*)d_in[5];
  const float* Wk = (const float*)d_in[6];
  const float* bk = (const float*)d_in[7];
  const float* Wv = (const float*)d_in[8];
  const float* bv = (const float*)d_in[9];
  const float* Wo = (const float*)d_in[10];
  const float* bo = (const float*)d_in[11];
  const float* rel_bias = (const float*)d_in[12];

  float* out_f    = (float*)d_out;                     //  4,194,304 floats
  float* attn_f   = out_f + (size_t)4194304;           // 67,108,864 floats
  float* scores_f = attn_f + (size_t)67108864;         // 67,108,864 floats

  char* ws = (char*)d_ws;
  bf16_t* qbf  = (bf16_t*)(ws);                        // (4096,1024) 8MB
  bf16_t* kbf  = (bf16_t*)(ws + (8ull  << 20));        // 8MB
  bf16_t* vbf  = (bf16_t*)(ws + (16ull << 20));        // 8MB
  bf16_t* Wqb  = (bf16_t*)(ws + (24ull << 20));        // 2MB
  bf16_t* Wkb  = (bf16_t*)(ws + (26ull << 20));        // 2MB
  bf16_t* Wvb  = (bf16_t*)(ws + (28ull << 20));        // 2MB
  bf16_t* Wob  = (bf16_t*)(ws + (30ull << 20));        // 2MB
  bf16_t* Qbf  = (bf16_t*)(ws + (32ull << 20));        // (B,H,S,D) 8MB
  bf16_t* Kbf  = (bf16_t*)(ws + (40ull << 20));        // (B,H,S,D) 8MB
  bf16_t* Vtbf = (bf16_t*)(ws + (48ull << 20));        // (B,H,D,S) 8MB
  bf16_t* CTX  = (bf16_t*)(ws + (56ull << 20));        // (B,S,E)   8MB

  dim3 blk(256);
  convert_kernel<<<dim3(8192), blk, 0, stream>>>(query, key, value, Wq, Wk, Wv, Wo,
                                                 qbf, kbf, vbf, Wqb, Wkb, Wvb, Wob);
  dim3 gproj(8, 32);
  proj_gemm<<<gproj, blk, 0, stream>>>(qbf, Wqb, bq, Qbf, nullptr, nullptr, 0);
  proj_gemm<<<gproj, blk, 0, stream>>>(kbf, Wkb, bk, Kbf, nullptr, nullptr, 0);
  proj_gemm<<<gproj, blk, 0, stream>>>(vbf, Wvb, bv, nullptr, Vtbf, nullptr, 2);
  fused_attn<<<dim3(16, 64), blk, 0, stream>>>(Qbf, Kbf, Vtbf, mask, rel_bias,
                                               scores_f, attn_f, CTX);
  proj_gemm<<<gproj, blk, 0, stream>>>(CTX, Wob, bo, nullptr, nullptr, out_f, 3);
}

// Round 6
// 460.663 us; speedup vs baseline: 1.2584x; 1.1255x over previous
//
#include <hip/hip_runtime.h>

typedef __bf16 bf16_t;
typedef bf16_t bf16x4 __attribute__((ext_vector_type(4)));
typedef bf16_t bf16x8 __attribute__((ext_vector_type(8)));
typedef float f32x4 __attribute__((ext_vector_type(4)));
typedef float f32x8 __attribute__((ext_vector_type(8)));

#define B_N 4
#define S_N 1024
#define E_N 1024
#define H_N 16
#define D_N 64

#define MFMA16 __builtin_amdgcn_mfma_f32_16x16x32_bf16

static __device__ __forceinline__ bf16_t f2b(float x) { return (bf16_t)x; }

// ---------------------------------------------------------------------------
// One-shot fp32 -> bf16 conversion of q,k,v (4096x1024 each) and the four
// weight matrices (1024x1024 each). Total 3*2^22 + 4*2^20 = 2^24 elements.
// ---------------------------------------------------------------------------
__global__ __launch_bounds__(256) void convert_kernel(
    const float* __restrict__ q, const float* __restrict__ k, const float* __restrict__ v,
    const float* __restrict__ wq, const float* __restrict__ wk,
    const float* __restrict__ wv, const float* __restrict__ wo,
    bf16_t* __restrict__ dq, bf16_t* __restrict__ dk, bf16_t* __restrict__ dv,
    bf16_t* __restrict__ dwq, bf16_t* __restrict__ dwk,
    bf16_t* __restrict__ dwv, bf16_t* __restrict__ dwo)
{
  const size_t e = ((size_t)blockIdx.x * 256 + threadIdx.x) * 8;
  const float* src; bf16_t* dst; size_t off;
  if (e < 12582912ull) {                       // q | k | v (4M elems each)
    const int which = (int)(e >> 22);
    off = e & 4194303ull;
    src = which == 0 ? q : (which == 1 ? k : v);
    dst = which == 0 ? dq : (which == 1 ? dk : dv);
  } else {                                     // Wq | Wk | Wv | Wo (1M each)
    const size_t e2 = e - 12582912ull;
    const int which = (int)(e2 >> 20);
    off = e2 & 1048575ull;
    src = which == 0 ? wq : (which == 1 ? wk : (which == 2 ? wv : wo));
    dst = which == 0 ? dwq : (which == 1 ? dwk : (which == 2 ? dwv : dwo));
  }
  f32x8 x = *(const f32x8*)(src + off);
  bf16x8 r;
#pragma unroll
  for (int i = 0; i < 8; ++i) r[i] = f2b(x[i]);
  *(bf16x8*)(dst + off) = r;
}

// ---------------------------------------------------------------------------
// Batched QKV projection GEMM: z = blockIdx.z selects (A, W, bias, output).
// C[m,n] = sum_k A[m,k]*W[n,k] + bias[n]
// z=0 -> Q (B,H,S,D); z=1 -> K (B,H,S,D); z=2 -> V^T (B,H,D,S).
// 128x128 tile, BK=32, 4 waves (2x2), 4x4 frags of 16x16x32 each.
// ---------------------------------------------------------------------------
__global__ __launch_bounds__(256) void qkv_gemm(
    const bf16_t* __restrict__ qA, const bf16_t* __restrict__ kA, const bf16_t* __restrict__ vA,
    const bf16_t* __restrict__ Wq, const bf16_t* __restrict__ Wk, const bf16_t* __restrict__ Wv,
    const float* __restrict__ bq, const float* __restrict__ bk, const float* __restrict__ bv,
    bf16_t* __restrict__ Qo, bf16_t* __restrict__ Ko, bf16_t* __restrict__ Vto)
{
  const int z = blockIdx.z;
  const bf16_t* A = z == 0 ? qA : (z == 1 ? kA : vA);
  const bf16_t* W = z == 0 ? Wq : (z == 1 ? Wk : Wv);
  const float* bias = z == 0 ? bq : (z == 1 ? bk : bv);

  constexpr int LDT = 40;
  __shared__ bf16_t As[128 * LDT];
  __shared__ bf16_t Bs[128 * LDT];
  const int tid = threadIdx.x;
  const int m0 = blockIdx.y * 128, n0 = blockIdx.x * 128;
  const int lane = tid & 63, wid = tid >> 6;
  const int wr = wid >> 1, wc = wid & 1;
  const int lr = lane & 15, lh = lane >> 4;
  f32x4 acc[4][4] = {};
  for (int k0 = 0; k0 < 1024; k0 += 32) {
#pragma unroll
    for (int i = 0; i < 2; ++i) {
      int f = tid + i * 256;
      int r = f >> 2, c = (f & 3) * 8;
      *(bf16x8*)&As[r * LDT + c] = *(const bf16x8*)&A[(size_t)(m0 + r) * 1024 + k0 + c];
      *(bf16x8*)&Bs[r * LDT + c] = *(const bf16x8*)&W[(size_t)(n0 + r) * 1024 + k0 + c];
    }
    __syncthreads();
    bf16x8 af[4], bw[4];
#pragma unroll
    for (int m = 0; m < 4; ++m)
      af[m] = *(const bf16x8*)&As[(wr * 64 + m * 16 + lr) * LDT + lh * 8];
#pragma unroll
    for (int n = 0; n < 4; ++n)
      bw[n] = *(const bf16x8*)&Bs[(wc * 64 + n * 16 + lr) * LDT + lh * 8];
#pragma unroll
    for (int m = 0; m < 4; ++m)
#pragma unroll
      for (int n = 0; n < 4; ++n)
        acc[m][n] = MFMA16(af[m], bw[n], acc[m][n], 0, 0, 0);
    __syncthreads();
  }
#pragma unroll
  for (int n = 0; n < 4; ++n) {
    const int col = n0 + wc * 64 + n * 16 + lr;
    const float bv_ = bias[col];
    const int h = col >> 6, d = col & 63;
#pragma unroll
    for (int m = 0; m < 4; ++m) {
      const int row0 = m0 + wr * 64 + m * 16 + lh * 4;
#pragma unroll
      for (int r = 0; r < 4; ++r) {
        const int row = row0 + r;
        const float v = acc[m][n][r] + bv_;
        const int b = row >> 10, s = row & 1023;
        if (z == 0)
          Qo[((size_t)(b * H_N + h) * S_N + s) * D_N + d] = f2b(v);
        else if (z == 1)
          Ko[((size_t)(b * H_N + h) * S_N + s) * D_N + d] = f2b(v);
        else
          Vto[((size_t)(b * H_N + h) * D_N + d) * S_N + s] = f2b(v);
      }
    }
  }
}

// ---------------------------------------------------------------------------
// Output projection: C[m,n] = sum_k A[m,k]*W[n,k] + bias[n], fp32 out.
// ---------------------------------------------------------------------------
__global__ __launch_bounds__(256) void out_gemm(
    const bf16_t* __restrict__ A, const bf16_t* __restrict__ W,
    const float* __restrict__ bias, float* __restrict__ Co)
{
  constexpr int LDT = 40;
  __shared__ bf16_t As[128 * LDT];
  __shared__ bf16_t Bs[128 * LDT];
  const int tid = threadIdx.x;
  const int m0 = blockIdx.y * 128, n0 = blockIdx.x * 128;
  const int lane = tid & 63, wid = tid >> 6;
  const int wr = wid >> 1, wc = wid & 1;
  const int lr = lane & 15, lh = lane >> 4;
  f32x4 acc[4][4] = {};
  for (int k0 = 0; k0 < 1024; k0 += 32) {
#pragma unroll
    for (int i = 0; i < 2; ++i) {
      int f = tid + i * 256;
      int r = f >> 2, c = (f & 3) * 8;
      *(bf16x8*)&As[r * LDT + c] = *(const bf16x8*)&A[(size_t)(m0 + r) * 1024 + k0 + c];
      *(bf16x8*)&Bs[r * LDT + c] = *(const bf16x8*)&W[(size_t)(n0 + r) * 1024 + k0 + c];
    }
    __syncthreads();
    bf16x8 af[4], bw[4];
#pragma unroll
    for (int m = 0; m < 4; ++m)
      af[m] = *(const bf16x8*)&As[(wr * 64 + m * 16 + lr) * LDT + lh * 8];
#pragma unroll
    for (int n = 0; n < 4; ++n)
      bw[n] = *(const bf16x8*)&Bs[(wc * 64 + n * 16 + lr) * LDT + lh * 8];
#pragma unroll
    for (int m = 0; m < 4; ++m)
#pragma unroll
      for (int n = 0; n < 4; ++n)
        acc[m][n] = MFMA16(af[m], bw[n], acc[m][n], 0, 0, 0);
    __syncthreads();
  }
#pragma unroll
  for (int n = 0; n < 4; ++n) {
    const int col = n0 + wc * 64 + n * 16 + lr;
    const float bv_ = bias[col];
#pragma unroll
    for (int m = 0; m < 4; ++m) {
      const int row0 = m0 + wr * 64 + m * 16 + lh * 4;
#pragma unroll
      for (int r = 0; r < 4; ++r)
        Co[(size_t)(row0 + r) * E_N + col] = acc[m][n][r] + bv_;
    }
  }
}

// ---------------------------------------------------------------------------
// s4: bias + scale + mask for 4 consecutive k at (qrow, kc..kc+3)
// ---------------------------------------------------------------------------
static __device__ __forceinline__ f32x4 score4(
    f32x4 acc, int qrow, int kc, const unsigned char* __restrict__ mrow,
    const float* __restrict__ rbh, float rb_lo, float rb_hi)
{
  const int d0 = kc - qrow;
  float b0, b1, b2, b3;
  if (d0 >= 8) { b0 = b1 = b2 = b3 = rb_hi; }
  else if (d0 <= -11) { b0 = b1 = b2 = b3 = rb_lo; }
  else {
    int dd;
    dd = d0;     dd = dd < -8 ? -8 : (dd > 8 ? 8 : dd); b0 = rbh[dd + 8];
    dd = d0 + 1; dd = dd < -8 ? -8 : (dd > 8 ? 8 : dd); b1 = rbh[dd + 8];
    dd = d0 + 2; dd = dd < -8 ? -8 : (dd > 8 ? 8 : dd); b2 = rbh[dd + 8];
    dd = d0 + 3; dd = dd < -8 ? -8 : (dd > 8 ? 8 : dd); b3 = rbh[dd + 8];
  }
  const unsigned int mw = *(const unsigned int*)(mrow + kc);
  const float NEG = -__builtin_inff();
  f32x4 s;
  s[0] = (mw & 0xffu)       ? NEG : acc[0] * 0.125f + b0;
  s[1] = (mw & 0xff00u)     ? NEG : acc[1] * 0.125f + b1;
  s[2] = (mw & 0xff0000u)   ? NEG : acc[2] * 0.125f + b2;
  s[3] = (mw & 0xff000000u) ? NEG : acc[3] * 0.125f + b3;
  return s;
}

// ---------------------------------------------------------------------------
// Fused attention, swapped-QK layout, recompute instead of re-read.
// Block = 1 wave = 16 q-rows of one (b,h). Lane owns q-row q0+(lane&15);
// swapped mfma(K,Q) gives lane 4 CONSECUTIVE k per slot -> f32x4 stores,
// uchar4 mask loads, lane-local online softmax (2 shfls to finish).
// P1: s -> scores (coalesced), online (max,sum).
// P2: recompute s (L2-hot K), p=exp(s-m)*invs -> attn; p->bf16 via 4KB LDS
//     bounce -> PV A-frags; PV MFMA vs Vt; ctx -> (B,S,E).
// ---------------------------------------------------------------------------
__global__ __launch_bounds__(64) void fused_attn(
    const bf16_t* __restrict__ Q, const bf16_t* __restrict__ K,
    const bf16_t* __restrict__ Vt,
    const unsigned char* __restrict__ mask, const float* __restrict__ rel_bias,
    float* __restrict__ scores, float* __restrict__ attn, bf16_t* __restrict__ ctx)
{
  __shared__ bf16_t P_lds[16 * 132];           // pitch 132 elems = 264B
  const int bh = blockIdx.y, b = bh >> 4, h = bh & 15;
  const int q0 = blockIdx.x * 16;
  const int lane = threadIdx.x;
  const int lr = lane & 15, lh = lane >> 4;
  const int qrow = q0 + lr;

  const bf16_t* Qh = Q + (size_t)bh * (S_N * D_N);
  const bf16_t* Kh = K + (size_t)bh * (S_N * D_N);
  const bf16_t* Vh = Vt + (size_t)bh * (D_N * S_N);
  const unsigned char* mrow = mask + (size_t)b * S_N * S_N + (size_t)qrow * S_N;
  float* Srow = scores + (size_t)bh * S_N * S_N + (size_t)qrow * S_N;
  float* Arow = attn + (size_t)bh * S_N * S_N + (size_t)qrow * S_N;
  const float* rbh = rel_bias + h * 17;
  const float rb_lo = rbh[0], rb_hi = rbh[16];
  const float NEG = -__builtin_inff();

  // Q fragment for q-row qrow (held entire kernel)
  bf16x8 qa0 = *(const bf16x8*)&Qh[(size_t)qrow * D_N + lh * 8];
  bf16x8 qa1 = *(const bf16x8*)&Qh[(size_t)qrow * D_N + 32 + lh * 8];

  // ---- P1: scores + online (max,sum) --------------------------------------
  float mrun = NEG, srun = 0.f;
  for (int kt = 0; kt < 8; ++kt) {
#pragma unroll
    for (int t = 0; t < 8; ++t) {
      const int kb = kt * 128 + t * 16;
      bf16x8 ka0 = *(const bf16x8*)&Kh[(size_t)(kb + lr) * D_N + lh * 8];
      bf16x8 ka1 = *(const bf16x8*)&Kh[(size_t)(kb + lr) * D_N + 32 + lh * 8];
      f32x4 acc = {};
      acc = MFMA16(ka0, qa0, acc, 0, 0, 0);    // D[k_idx][q_idx]
      acc = MFMA16(ka1, qa1, acc, 0, 0, 0);
      const int kc = kb + 4 * lh;
      f32x4 s = score4(acc, qrow, kc, mrow, rbh, rb_lo, rb_hi);
      *(f32x4*)&Srow[kc] = s;
      const float mt = fmaxf(fmaxf(s[0], s[1]), fmaxf(s[2], s[3]));
      const float mn = fmaxf(mrun, mt);
      if (mn > NEG) {                           // guard fully-masked prefix
        srun = srun * __expf(mrun - mn)
             + __expf(s[0] - mn) + __expf(s[1] - mn)
             + __expf(s[2] - mn) + __expf(s[3] - mn);
        mrun = mn;
      }
    }
  }
  // combine across the 4 lanes sharing this q-row (lane^16, lane^32)
#pragma unroll
  for (int off = 16; off <= 32; off <<= 1) {
    const float m2 = __shfl_xor(mrun, off);
    const float s2 = __shfl_xor(srun, off);
    const float mn = fmaxf(mrun, m2);
    if (mn > NEG) {
      srun = srun * __expf(mrun - mn) + s2 * __expf(m2 - mn);
      mrun = mn;
    }
  }
  const float invs = 1.0f / srun;

  // ---- P2: recompute, attn write, PV --------------------------------------
  f32x4 accp[4] = {};
  for (int kt = 0; kt < 8; ++kt) {
#pragma unroll
    for (int t = 0; t < 8; ++t) {
      const int kb = kt * 128 + t * 16;
      bf16x8 ka0 = *(const bf16x8*)&Kh[(size_t)(kb + lr) * D_N + lh * 8];
      bf16x8 ka1 = *(const bf16x8*)&Kh[(size_t)(kb + lr) * D_N + 32 + lh * 8];
      f32x4 acc = {};
      acc = MFMA16(ka0, qa0, acc, 0, 0, 0);
      acc = MFMA16(ka1, qa1, acc, 0, 0, 0);
      const int kc = kb + 4 * lh;
      f32x4 s = score4(acc, qrow, kc, mrow, rbh, rb_lo, rb_hi);
      f32x4 p; bf16x4 pb;
#pragma unroll
      for (int j = 0; j < 4; ++j) {
        p[j] = __expf(s[j] - mrun) * invs;
        pb[j] = f2b(p[j]);
      }
      *(f32x4*)&Arow[kc] = p;
      *(bf16x4*)&P_lds[lr * 132 + t * 16 + 4 * lh] = pb;   // wave-local LDS
    }
    // PV for this 128-k tile: A-frag = P_lds row lr, k = ch*32 + lh*8 + j
#pragma unroll
    for (int ch = 0; ch < 4; ++ch) {
      bf16x4 lo = *(const bf16x4*)&P_lds[lr * 132 + ch * 32 + lh * 8];
      bf16x4 hi = *(const bf16x4*)&P_lds[lr * 132 + ch * 32 + lh * 8 + 4];
      bf16x8 pa;
#pragma unroll
      for (int j = 0; j < 4; ++j) { pa[j] = lo[j]; pa[4 + j] = hi[j]; }
#pragma unroll
      for (int dt = 0; dt < 4; ++dt) {
        bf16x8 vb = *(const bf16x8*)&Vh[(size_t)(dt * 16 + lr) * S_N + kt * 128 + ch * 32 + lh * 8];
        accp[dt] = MFMA16(pa, vb, accp[dt], 0, 0, 0);      // D[q_idx][d_idx]
      }
    }
  }
  // ctx epilogue: lane holds q = q0+4lh+r, d = dt*16+lr
#pragma unroll
  for (int dt = 0; dt < 4; ++dt)
#pragma unroll
    for (int r = 0; r < 4; ++r)
      ctx[((size_t)(b * S_N + q0 + 4 * lh + r)) * E_N + h * 64 + dt * 16 + lr] =
          f2b(accp[dt][r]);
}

// ---------------------------------------------------------------------------
extern "C" void kernel_launch(void* const* d_in, const int* in_sizes, int n_in,
                              void* d_out, int out_size, void* d_ws, size_t ws_size,
                              hipStream_t stream) {
  (void)in_sizes; (void)n_in; (void)out_size; (void)ws_size;
  const float* query = (const float*)d_in[0];
  const float* key   = (const float*)d_in[1];
  const float* value = (const float*)d_in[2];
  const unsigned char* mask = (const unsigned char*)d_in[3];
  const float* Wq = (const float*)d_in[4];
  const float* bq = (const float*)d_in[5];
  const float* Wk = (const float*)d_in[6];
  const float* bk = (const float*)d_in[7];
  const float* Wv = (const float*)d_in[8];
  const float* bv = (const float*)d_in[9];
  const float* Wo = (const float*)d_in[10];
  const float* bo = (const float*)d_in[11];
  const float* rel_bias = (const float*)d_in[12];

  float* out_f    = (float*)d_out;                     //  4,194,304 floats
  float* attn_f   = out_f + (size_t)4194304;           // 67,108,864 floats
  float* scores_f = attn_f + (size_t)67108864;         // 67,108,864 floats

  char* ws = (char*)d_ws;                              // ~2GiB available; 64MB used
  bf16_t* qbf  = (bf16_t*)(ws);                        // (4096,1024) 8MB
  bf16_t* kbf  = (bf16_t*)(ws + (8ull  << 20));        // 8MB
  bf16_t* vbf  = (bf16_t*)(ws + (16ull << 20));        // 8MB
  bf16_t* Wqb  = (bf16_t*)(ws + (24ull << 20));        // 2MB
  bf16_t* Wkb  = (bf16_t*)(ws + (26ull << 20));        // 2MB
  bf16_t* Wvb  = (bf16_t*)(ws + (28ull << 20));        // 2MB
  bf16_t* Wob  = (bf16_t*)(ws + (30ull << 20));        // 2MB
  bf16_t* Qbf  = (bf16_t*)(ws + (32ull << 20));        // (B,H,S,D) 8MB
  bf16_t* Kbf  = (bf16_t*)(ws + (40ull << 20));        // (B,H,S,D) 8MB
  bf16_t* Vtbf = (bf16_t*)(ws + (48ull << 20));        // (B,H,D,S) 8MB
  bf16_t* CTX  = (bf16_t*)(ws + (56ull << 20));        // (B,S,E)   8MB

  convert_kernel<<<dim3(8192), dim3(256), 0, stream>>>(
      query, key, value, Wq, Wk, Wv, Wo, qbf, kbf, vbf, Wqb, Wkb, Wvb, Wob);
  qkv_gemm<<<dim3(8, 32, 3), dim3(256), 0, stream>>>(
      qbf, kbf, vbf, Wqb, Wkb, Wvb, bq, bk, bv, Qbf, Kbf, Vtbf);
  fused_attn<<<dim3(64, 64), dim3(64), 0, stream>>>(
      Qbf, Kbf, Vtbf, mask, rel_bias, scores_f, attn_f, CTX);
  out_gemm<<<dim3(8, 32), dim3(256), 0, stream>>>(CTX, Wob, bo, out_f);
}

// Round 7
// 438.859 us; speedup vs baseline: 1.3209x; 1.0497x over previous
//
#include <hip/hip_runtime.h>

typedef __bf16 bf16_t;
typedef bf16_t bf16x4 __attribute__((ext_vector_type(4)));
typedef bf16_t bf16x8 __attribute__((ext_vector_type(8)));
typedef float f32x4 __attribute__((ext_vector_type(4)));
typedef float f32x8 __attribute__((ext_vector_type(8)));

#define B_N 4
#define S_N 1024
#define E_N 1024
#define H_N 16
#define D_N 64

#define MFMA16 __builtin_amdgcn_mfma_f32_16x16x32_bf16

static __device__ __forceinline__ bf16_t f2b(float x) { return (bf16_t)x; }

// ---------------------------------------------------------------------------
// One-shot fp32 -> bf16 conversion of q,k,v (4096x1024 each) and the four
// weight matrices (1024x1024 each). Total 3*2^22 + 4*2^20 = 2^24 elements.
// ---------------------------------------------------------------------------
__global__ __launch_bounds__(256) void convert_kernel(
    const float* __restrict__ q, const float* __restrict__ k, const float* __restrict__ v,
    const float* __restrict__ wq, const float* __restrict__ wk,
    const float* __restrict__ wv, const float* __restrict__ wo,
    bf16_t* __restrict__ dq, bf16_t* __restrict__ dk, bf16_t* __restrict__ dv,
    bf16_t* __restrict__ dwq, bf16_t* __restrict__ dwk,
    bf16_t* __restrict__ dwv, bf16_t* __restrict__ dwo)
{
  const size_t e = ((size_t)blockIdx.x * 256 + threadIdx.x) * 8;
  const float* src; bf16_t* dst; size_t off;
  if (e < 12582912ull) {                       // q | k | v (4M elems each)
    const int which = (int)(e >> 22);
    off = e & 4194303ull;
    src = which == 0 ? q : (which == 1 ? k : v);
    dst = which == 0 ? dq : (which == 1 ? dk : dv);
  } else {                                     // Wq | Wk | Wv | Wo (1M each)
    const size_t e2 = e - 12582912ull;
    const int which = (int)(e2 >> 20);
    off = e2 & 1048575ull;
    src = which == 0 ? wq : (which == 1 ? wk : (which == 2 ? wv : wo));
    dst = which == 0 ? dwq : (which == 1 ? dwk : (which == 2 ? dwv : dwo));
  }
  f32x8 x = *(const f32x8*)(src + off);
  bf16x8 r;
#pragma unroll
  for (int i = 0; i < 8; ++i) r[i] = f2b(x[i]);
  *(bf16x8*)(dst + off) = r;
}

// ---------------------------------------------------------------------------
// Batched QKV projection GEMM: z selects (A, W, bias, output layout).
// z=0 -> Q (B,H,S,D); z=1 -> K (B,H,S,D); z=2 -> V^T (B,H,D,S).
// ---------------------------------------------------------------------------
__global__ __launch_bounds__(256) void qkv_gemm(
    const bf16_t* __restrict__ qA, const bf16_t* __restrict__ kA, const bf16_t* __restrict__ vA,
    const bf16_t* __restrict__ Wq, const bf16_t* __restrict__ Wk, const bf16_t* __restrict__ Wv,
    const float* __restrict__ bq, const float* __restrict__ bk, const float* __restrict__ bv,
    bf16_t* __restrict__ Qo, bf16_t* __restrict__ Ko, bf16_t* __restrict__ Vto)
{
  const int z = blockIdx.z;
  const bf16_t* A = z == 0 ? qA : (z == 1 ? kA : vA);
  const bf16_t* W = z == 0 ? Wq : (z == 1 ? Wk : Wv);
  const float* bias = z == 0 ? bq : (z == 1 ? bk : bv);

  constexpr int LDT = 40;
  __shared__ bf16_t As[128 * LDT];
  __shared__ bf16_t Bs[128 * LDT];
  const int tid = threadIdx.x;
  const int m0 = blockIdx.y * 128, n0 = blockIdx.x * 128;
  const int lane = tid & 63, wid = tid >> 6;
  const int wr = wid >> 1, wc = wid & 1;
  const int lr = lane & 15, lh = lane >> 4;
  f32x4 acc[4][4] = {};
  for (int k0 = 0; k0 < 1024; k0 += 32) {
#pragma unroll
    for (int i = 0; i < 2; ++i) {
      int f = tid + i * 256;
      int r = f >> 2, c = (f & 3) * 8;
      *(bf16x8*)&As[r * LDT + c] = *(const bf16x8*)&A[(size_t)(m0 + r) * 1024 + k0 + c];
      *(bf16x8*)&Bs[r * LDT + c] = *(const bf16x8*)&W[(size_t)(n0 + r) * 1024 + k0 + c];
    }
    __syncthreads();
    bf16x8 af[4], bw[4];
#pragma unroll
    for (int m = 0; m < 4; ++m)
      af[m] = *(const bf16x8*)&As[(wr * 64 + m * 16 + lr) * LDT + lh * 8];
#pragma unroll
    for (int n = 0; n < 4; ++n)
      bw[n] = *(const bf16x8*)&Bs[(wc * 64 + n * 16 + lr) * LDT + lh * 8];
#pragma unroll
    for (int m = 0; m < 4; ++m)
#pragma unroll
      for (int n = 0; n < 4; ++n)
        acc[m][n] = MFMA16(af[m], bw[n], acc[m][n], 0, 0, 0);
    __syncthreads();
  }
#pragma unroll
  for (int n = 0; n < 4; ++n) {
    const int col = n0 + wc * 64 + n * 16 + lr;
    const float bv_ = bias[col];
    const int h = col >> 6, d = col & 63;
#pragma unroll
    for (int m = 0; m < 4; ++m) {
      const int row0 = m0 + wr * 64 + m * 16 + lh * 4;
#pragma unroll
      for (int r = 0; r < 4; ++r) {
        const int row = row0 + r;
        const float v = acc[m][n][r] + bv_;
        const int b = row >> 10, s = row & 1023;
        if (z == 0)
          Qo[((size_t)(b * H_N + h) * S_N + s) * D_N + d] = f2b(v);
        else if (z == 1)
          Ko[((size_t)(b * H_N + h) * S_N + s) * D_N + d] = f2b(v);
        else
          Vto[((size_t)(b * H_N + h) * D_N + d) * S_N + s] = f2b(v);
      }
    }
  }
}

// ---------------------------------------------------------------------------
// Output projection: C[m,n] = sum_k A[m,k]*W[n,k] + bias[n], fp32 out.
// ---------------------------------------------------------------------------
__global__ __launch_bounds__(256) void out_gemm(
    const bf16_t* __restrict__ A, const bf16_t* __restrict__ W,
    const float* __restrict__ bias, float* __restrict__ Co)
{
  constexpr int LDT = 40;
  __shared__ bf16_t As[128 * LDT];
  __shared__ bf16_t Bs[128 * LDT];
  const int tid = threadIdx.x;
  const int m0 = blockIdx.y * 128, n0 = blockIdx.x * 128;
  const int lane = tid & 63, wid = tid >> 6;
  const int wr = wid >> 1, wc = wid & 1;
  const int lr = lane & 15, lh = lane >> 4;
  f32x4 acc[4][4] = {};
  for (int k0 = 0; k0 < 1024; k0 += 32) {
#pragma unroll
    for (int i = 0; i < 2; ++i) {
      int f = tid + i * 256;
      int r = f >> 2, c = (f & 3) * 8;
      *(bf16x8*)&As[r * LDT + c] = *(const bf16x8*)&A[(size_t)(m0 + r) * 1024 + k0 + c];
      *(bf16x8*)&Bs[r * LDT + c] = *(const bf16x8*)&W[(size_t)(n0 + r) * 1024 + k0 + c];
    }
    __syncthreads();
    bf16x8 af[4], bw[4];
#pragma unroll
    for (int m = 0; m < 4; ++m)
      af[m] = *(const bf16x8*)&As[(wr * 64 + m * 16 + lr) * LDT + lh * 8];
#pragma unroll
    for (int n = 0; n < 4; ++n)
      bw[n] = *(const bf16x8*)&Bs[(wc * 64 + n * 16 + lr) * LDT + lh * 8];
#pragma unroll
    for (int m = 0; m < 4; ++m)
#pragma unroll
      for (int n = 0; n < 4; ++n)
        acc[m][n] = MFMA16(af[m], bw[n], acc[m][n], 0, 0, 0);
    __syncthreads();
  }
#pragma unroll
  for (int n = 0; n < 4; ++n) {
    const int col = n0 + wc * 64 + n * 16 + lr;
    const float bv_ = bias[col];
#pragma unroll
    for (int m = 0; m < 4; ++m) {
      const int row0 = m0 + wr * 64 + m * 16 + lh * 4;
#pragma unroll
      for (int r = 0; r < 4; ++r)
        Co[(size_t)(row0 + r) * E_N + col] = acc[m][n][r] + bv_;
    }
  }
}

// ---------------------------------------------------------------------------
// score4: scale + rel_bias + mask for 4 consecutive k at (qrow, kc..kc+3)
// ---------------------------------------------------------------------------
static __device__ __forceinline__ f32x4 score4(
    f32x4 acc, int qrow, int kc, const unsigned char* __restrict__ mrow,
    const float* __restrict__ rbh, float rb_lo, float rb_hi)
{
  const int d0 = kc - qrow;
  float b0, b1, b2, b3;
  if (d0 >= 8) { b0 = b1 = b2 = b3 = rb_hi; }
  else if (d0 <= -11) { b0 = b1 = b2 = b3 = rb_lo; }
  else {
    int dd;
    dd = d0;     dd = dd < -8 ? -8 : (dd > 8 ? 8 : dd); b0 = rbh[dd + 8];
    dd = d0 + 1; dd = dd < -8 ? -8 : (dd > 8 ? 8 : dd); b1 = rbh[dd + 8];
    dd = d0 + 2; dd = dd < -8 ? -8 : (dd > 8 ? 8 : dd); b2 = rbh[dd + 8];
    dd = d0 + 3; dd = dd < -8 ? -8 : (dd > 8 ? 8 : dd); b3 = rbh[dd + 8];
  }
  const unsigned int mw = *(const unsigned int*)(mrow + kc);
  const float NEG = -__builtin_inff();
  f32x4 s;
  s[0] = (mw & 0xffu)       ? NEG : acc[0] * 0.125f + b0;
  s[1] = (mw & 0xff00u)     ? NEG : acc[1] * 0.125f + b1;
  s[2] = (mw & 0xff0000u)   ? NEG : acc[2] * 0.125f + b2;
  s[3] = (mw & 0xff000000u) ? NEG : acc[3] * 0.125f + b3;
  return s;
}

// ---------------------------------------------------------------------------
// Fused attention, 4-way split-K inside the block.
// Block = 256 threads = 4 waves, one (bh, 16-q-row tile). Wave w owns
// k in [256w, 256w+256). Swapped mfma(K,Q): lane lr owns q-row q0+lr,
// 4 consecutive k per result slot. Online (max,sum) per wave-quarter,
// merged via LDS. P2 recomputes s (L2-hot K), writes attn, PV-accumulates
// its quarter; partial ctx summed via LDS (union'd with the P-bounce tile).
// ---------------------------------------------------------------------------
__global__ __launch_bounds__(256, 6) void fused_attn(
    const bf16_t* __restrict__ Q, const bf16_t* __restrict__ K,
    const bf16_t* __restrict__ Vt,
    const unsigned char* __restrict__ mask, const float* __restrict__ rel_bias,
    float* __restrict__ scores, float* __restrict__ attn, bf16_t* __restrict__ ctx)
{
  __shared__ char smem[16896];                 // P_lds [4][16][132]bf16 | ctxp [4][16][64]f32
  __shared__ float2 stats[4][16];
  bf16_t* P_lds = (bf16_t*)smem;
  float (*ctxp)[16][64] = (float (*)[16][64])smem;

  const int bh = blockIdx.y, b = bh >> 4, h = bh & 15;
  const int q0 = blockIdx.x * 16;
  const int tid = threadIdx.x;
  const int w = tid >> 6, lane = tid & 63;
  const int lr = lane & 15, lh = lane >> 4;
  const int qrow = q0 + lr;
  const int kbase = w * 256;                   // this wave's k-quarter

  const bf16_t* Qh = Q + (size_t)bh * (S_N * D_N);
  const bf16_t* Kh = K + (size_t)bh * (S_N * D_N);
  const bf16_t* Vh = Vt + (size_t)bh * (D_N * S_N);
  const unsigned char* mrow = mask + (size_t)b * S_N * S_N + (size_t)qrow * S_N;
  float* Srow = scores + (size_t)bh * S_N * S_N + (size_t)qrow * S_N;
  float* Arow = attn + (size_t)bh * S_N * S_N + (size_t)qrow * S_N;
  const float* rbh = rel_bias + h * 17;
  const float rb_lo = rbh[0], rb_hi = rbh[16];
  const float NEG = -__builtin_inff();

  // Q fragment for q-row qrow (held entire kernel)
  bf16x8 qa0 = *(const bf16x8*)&Qh[(size_t)qrow * D_N + lh * 8];
  bf16x8 qa1 = *(const bf16x8*)&Qh[(size_t)qrow * D_N + 32 + lh * 8];

  // ---- P1: scores + online (max,sum) over this wave's 256-k quarter -------
  float mrun = NEG, srun = 0.f;
#pragma unroll 8
  for (int t = 0; t < 16; ++t) {
    const int kb = kbase + t * 16;
    bf16x8 ka0 = *(const bf16x8*)&Kh[(size_t)(kb + lr) * D_N + lh * 8];
    bf16x8 ka1 = *(const bf16x8*)&Kh[(size_t)(kb + lr) * D_N + 32 + lh * 8];
    f32x4 acc = {};
    acc = MFMA16(ka0, qa0, acc, 0, 0, 0);      // D[k_idx][q_idx]
    acc = MFMA16(ka1, qa1, acc, 0, 0, 0);
    const int kc = kb + 4 * lh;
    f32x4 s = score4(acc, qrow, kc, mrow, rbh, rb_lo, rb_hi);
    *(f32x4*)&Srow[kc] = s;
    const float mt = fmaxf(fmaxf(s[0], s[1]), fmaxf(s[2], s[3]));
    const float mn = fmaxf(mrun, mt);
    if (mn > NEG) {
      srun = srun * __expf(mrun - mn)
           + __expf(s[0] - mn) + __expf(s[1] - mn)
           + __expf(s[2] - mn) + __expf(s[3] - mn);
      mrun = mn;
    }
  }
  // combine across the 4 lanes sharing this q-row (lane^16, lane^32)
#pragma unroll
  for (int off = 16; off <= 32; off <<= 1) {
    const float m2 = __shfl_xor(mrun, off);
    const float s2 = __shfl_xor(srun, off);
    const float mn = fmaxf(mrun, m2);
    if (mn > NEG) {
      srun = srun * __expf(mrun - mn) + s2 * __expf(m2 - mn);
      mrun = mn;
    }
  }
  if (lane < 16) stats[w][lr] = make_float2(mrun, srun);
  __syncthreads();
  // merge the 4 k-quarters (every lane; order-independent formula, fixed order)
  float M = NEG, SS = 0.f;
#pragma unroll
  for (int ww = 0; ww < 4; ++ww) {
    const float2 st = stats[ww][lr];
    const float mn = fmaxf(M, st.x);
    if (mn > NEG) {
      SS = SS * __expf(M - mn) + st.y * __expf(st.x - mn);
      M = mn;
    }
  }
  const float invs = 1.0f / SS;

  // ---- P2: recompute, attn write, PV over the quarter ----------------------
  bf16_t* Pw = P_lds + w * (16 * 132);
  f32x4 accp[4] = {};
  for (int kt2 = 0; kt2 < 2; ++kt2) {
#pragma unroll
    for (int t = 0; t < 8; ++t) {
      const int kb = kbase + kt2 * 128 + t * 16;
      bf16x8 ka0 = *(const bf16x8*)&Kh[(size_t)(kb + lr) * D_N + lh * 8];
      bf16x8 ka1 = *(const bf16x8*)&Kh[(size_t)(kb + lr) * D_N + 32 + lh * 8];
      f32x4 acc = {};
      acc = MFMA16(ka0, qa0, acc, 0, 0, 0);
      acc = MFMA16(ka1, qa1, acc, 0, 0, 0);
      const int kc = kb + 4 * lh;
      f32x4 s = score4(acc, qrow, kc, mrow, rbh, rb_lo, rb_hi);
      f32x4 p; bf16x4 pb;
#pragma unroll
      for (int j = 0; j < 4; ++j) {
        p[j] = __expf(s[j] - M) * invs;
        pb[j] = f2b(p[j]);
      }
      *(f32x4*)&Arow[kc] = p;
      *(bf16x4*)&Pw[lr * 132 + t * 16 + 4 * lh] = pb;     // wave-local LDS
    }
    // PV for this 128-k tile
#pragma unroll
    for (int ch = 0; ch < 4; ++ch) {
      bf16x4 lo = *(const bf16x4*)&Pw[lr * 132 + ch * 32 + lh * 8];
      bf16x4 hi = *(const bf16x4*)&Pw[lr * 132 + ch * 32 + lh * 8 + 4];
      bf16x8 pa;
#pragma unroll
      for (int j = 0; j < 4; ++j) { pa[j] = lo[j]; pa[4 + j] = hi[j]; }
#pragma unroll
      for (int dt = 0; dt < 4; ++dt) {
        bf16x8 vb = *(const bf16x8*)&Vh[(size_t)(dt * 16 + lr) * S_N + kbase + kt2 * 128 + ch * 32 + lh * 8];
        accp[dt] = MFMA16(pa, vb, accp[dt], 0, 0, 0);     // D[q_idx][d_idx]
      }
    }
  }

  // ---- partial-ctx reduction across the 4 k-quarters -----------------------
  __syncthreads();                              // all P_lds reads done (union!)
#pragma unroll
  for (int dt = 0; dt < 4; ++dt)
#pragma unroll
    for (int r = 0; r < 4; ++r)
      ctxp[w][4 * lh + r][dt * 16 + lr] = accp[dt][r];
  __syncthreads();
  const int ri = tid >> 4, dg = (tid & 15) * 4;
  f32x4 sum = *(const f32x4*)&ctxp[0][ri][dg];
#pragma unroll
  for (int ww = 1; ww < 4; ++ww) sum += *(const f32x4*)&ctxp[ww][ri][dg];
  bf16x4 cb;
#pragma unroll
  for (int j = 0; j < 4; ++j) cb[j] = f2b(sum[j]);
  *(bf16x4*)&ctx[((size_t)(b * S_N + q0 + ri)) * E_N + h * 64 + dg] = cb;
}

// ---------------------------------------------------------------------------
extern "C" void kernel_launch(void* const* d_in, const int* in_sizes, int n_in,
                              void* d_out, int out_size, void* d_ws, size_t ws_size,
                              hipStream_t stream) {
  (void)in_sizes; (void)n_in; (void)out_size; (void)ws_size;
  const float* query = (const float*)d_in[0];
  const float* key   = (const float*)d_in[1];
  const float* value = (const float*)d_in[2];
  const unsigned char* mask = (const unsigned char*)d_in[3];
  const float* Wq = (const float*)d_in[4];
  const float* bq = (const float*)d_in[5];
  const float* Wk = (const float*)d_in[6];
  const float* bk = (const float*)d_in[7];
  const float* Wv = (const float*)d_in[8];
  const float* bv = (const float*)d_in[9];
  const float* Wo = (const float*)d_in[10];
  const float* bo = (const float*)d_in[11];
  const float* rel_bias = (const float*)d_in[12];

  float* out_f    = (float*)d_out;                     //  4,194,304 floats
  float* attn_f   = out_f + (size_t)4194304;           // 67,108,864 floats
  float* scores_f = attn_f + (size_t)67108864;         // 67,108,864 floats

  char* ws = (char*)d_ws;                              // ~2GiB available; 64MB used
  bf16_t* qbf  = (bf16_t*)(ws);                        // (4096,1024) 8MB
  bf16_t* kbf  = (bf16_t*)(ws + (8ull  << 20));        // 8MB
  bf16_t* vbf  = (bf16_t*)(ws + (16ull << 20));        // 8MB
  bf16_t* Wqb  = (bf16_t*)(ws + (24ull << 20));        // 2MB
  bf16_t* Wkb  = (bf16_t*)(ws + (26ull << 20));        // 2MB
  bf16_t* Wvb  = (bf16_t*)(ws + (28ull << 20));        // 2MB
  bf16_t* Wob  = (bf16_t*)(ws + (30ull << 20));        // 2MB
  bf16_t* Qbf  = (bf16_t*)(ws + (32ull << 20));        // (B,H,S,D) 8MB
  bf16_t* Kbf  = (bf16_t*)(ws + (40ull << 20));        // (B,H,S,D) 8MB
  bf16_t* Vtbf = (bf16_t*)(ws + (48ull << 20));        // (B,H,D,S) 8MB
  bf16_t* CTX  = (bf16_t*)(ws + (56ull << 20));        // (B,S,E)   8MB

  convert_kernel<<<dim3(8192), dim3(256), 0, stream>>>(
      query, key, value, Wq, Wk, Wv, Wo, qbf, kbf, vbf, Wqb, Wkb, Wvb, Wob);
  qkv_gemm<<<dim3(8, 32, 3), dim3(256), 0, stream>>>(
      qbf, kbf, vbf, Wqb, Wkb, Wvb, bq, bk, bv, Qbf, Kbf, Vtbf);
  fused_attn<<<dim3(64, 64), dim3(256), 0, stream>>>(
      Qbf, Kbf, Vtbf, mask, rel_bias, scores_f, attn_f, CTX);
  out_gemm<<<dim3(8, 32), dim3(256), 0, stream>>>(CTX, Wob, bo, out_f);
}

// Round 8
// 376.191 us; speedup vs baseline: 1.5410x; 1.1666x over previous
//
#include <hip/hip_runtime.h>

typedef __bf16 bf16_t;
typedef bf16_t bf16x4 __attribute__((ext_vector_type(4)));
typedef bf16_t bf16x8 __attribute__((ext_vector_type(8)));
typedef float f32x4 __attribute__((ext_vector_type(4)));
typedef float f32x8 __attribute__((ext_vector_type(8)));

#define B_N 4
#define S_N 1024
#define E_N 1024
#define H_N 16
#define D_N 64

#define MFMA16 __builtin_amdgcn_mfma_f32_16x16x32_bf16

static __device__ __forceinline__ bf16_t f2b(float x) { return (bf16_t)x; }

// ---------------------------------------------------------------------------
// One-shot fp32 -> bf16 conversion of q,k,v (4096x1024 each) and the four
// weight matrices (1024x1024 each). Total 3*2^22 + 4*2^20 = 2^24 elements.
// ---------------------------------------------------------------------------
__global__ __launch_bounds__(256) void convert_kernel(
    const float* __restrict__ q, const float* __restrict__ k, const float* __restrict__ v,
    const float* __restrict__ wq, const float* __restrict__ wk,
    const float* __restrict__ wv, const float* __restrict__ wo,
    bf16_t* __restrict__ dq, bf16_t* __restrict__ dk, bf16_t* __restrict__ dv,
    bf16_t* __restrict__ dwq, bf16_t* __restrict__ dwk,
    bf16_t* __restrict__ dwv, bf16_t* __restrict__ dwo)
{
  const size_t e = ((size_t)blockIdx.x * 256 + threadIdx.x) * 8;
  const float* src; bf16_t* dst; size_t off;
  if (e < 12582912ull) {                       // q | k | v (4M elems each)
    const int which = (int)(e >> 22);
    off = e & 4194303ull;
    src = which == 0 ? q : (which == 1 ? k : v);
    dst = which == 0 ? dq : (which == 1 ? dk : dv);
  } else {                                     // Wq | Wk | Wv | Wo (1M each)
    const size_t e2 = e - 12582912ull;
    const int which = (int)(e2 >> 20);
    off = e2 & 1048575ull;
    src = which == 0 ? wq : (which == 1 ? wk : (which == 2 ? wv : wo));
    dst = which == 0 ? dwq : (which == 1 ? dwk : (which == 2 ? dwv : dwo));
  }
  f32x8 x = *(const f32x8*)(src + off);
  bf16x8 r;
#pragma unroll
  for (int i = 0; i < 8; ++i) r[i] = f2b(x[i]);
  *(bf16x8*)(dst + off) = r;
}

// ---------------------------------------------------------------------------
// Batched QKV projection GEMM: z selects (A, W, bias, output layout).
// z=0 -> Q (B,H,S,D); z=1 -> K (B,H,S,D); z=2 -> V^T (B,H,D,S).
// ---------------------------------------------------------------------------
__global__ __launch_bounds__(256) void qkv_gemm(
    const bf16_t* __restrict__ qA, const bf16_t* __restrict__ kA, const bf16_t* __restrict__ vA,
    const bf16_t* __restrict__ Wq, const bf16_t* __restrict__ Wk, const bf16_t* __restrict__ Wv,
    const float* __restrict__ bq, const float* __restrict__ bk, const float* __restrict__ bv,
    bf16_t* __restrict__ Qo, bf16_t* __restrict__ Ko, bf16_t* __restrict__ Vto)
{
  const int z = blockIdx.z;
  const bf16_t* A = z == 0 ? qA : (z == 1 ? kA : vA);
  const bf16_t* W = z == 0 ? Wq : (z == 1 ? Wk : Wv);
  const float* bias = z == 0 ? bq : (z == 1 ? bk : bv);

  constexpr int LDT = 40;
  __shared__ bf16_t As[128 * LDT];
  __shared__ bf16_t Bs[128 * LDT];
  const int tid = threadIdx.x;
  const int m0 = blockIdx.y * 128, n0 = blockIdx.x * 128;
  const int lane = tid & 63, wid = tid >> 6;
  const int wr = wid >> 1, wc = wid & 1;
  const int lr = lane & 15, lh = lane >> 4;
  f32x4 acc[4][4] = {};
  for (int k0 = 0; k0 < 1024; k0 += 32) {
#pragma unroll
    for (int i = 0; i < 2; ++i) {
      int f = tid + i * 256;
      int r = f >> 2, c = (f & 3) * 8;
      *(bf16x8*)&As[r * LDT + c] = *(const bf16x8*)&A[(size_t)(m0 + r) * 1024 + k0 + c];
      *(bf16x8*)&Bs[r * LDT + c] = *(const bf16x8*)&W[(size_t)(n0 + r) * 1024 + k0 + c];
    }
    __syncthreads();
    bf16x8 af[4], bw[4];
#pragma unroll
    for (int m = 0; m < 4; ++m)
      af[m] = *(const bf16x8*)&As[(wr * 64 + m * 16 + lr) * LDT + lh * 8];
#pragma unroll
    for (int n = 0; n < 4; ++n)
      bw[n] = *(const bf16x8*)&Bs[(wc * 64 + n * 16 + lr) * LDT + lh * 8];
#pragma unroll
    for (int m = 0; m < 4; ++m)
#pragma unroll
      for (int n = 0; n < 4; ++n)
        acc[m][n] = MFMA16(af[m], bw[n], acc[m][n], 0, 0, 0);
    __syncthreads();
  }
#pragma unroll
  for (int n = 0; n < 4; ++n) {
    const int col = n0 + wc * 64 + n * 16 + lr;
    const float bv_ = bias[col];
    const int h = col >> 6, d = col & 63;
#pragma unroll
    for (int m = 0; m < 4; ++m) {
      const int row0 = m0 + wr * 64 + m * 16 + lh * 4;
#pragma unroll
      for (int r = 0; r < 4; ++r) {
        const int row = row0 + r;
        const float v = acc[m][n][r] + bv_;
        const int b = row >> 10, s = row & 1023;
        if (z == 0)
          Qo[((size_t)(b * H_N + h) * S_N + s) * D_N + d] = f2b(v);
        else if (z == 1)
          Ko[((size_t)(b * H_N + h) * S_N + s) * D_N + d] = f2b(v);
        else
          Vto[((size_t)(b * H_N + h) * D_N + d) * S_N + s] = f2b(v);
      }
    }
  }
}

// ---------------------------------------------------------------------------
// Output projection: C[m,n] = sum_k A[m,k]*W[n,k] + bias[n], fp32 out.
// ---------------------------------------------------------------------------
__global__ __launch_bounds__(256) void out_gemm(
    const bf16_t* __restrict__ A, const bf16_t* __restrict__ W,
    const float* __restrict__ bias, float* __restrict__ Co)
{
  constexpr int LDT = 40;
  __shared__ bf16_t As[128 * LDT];
  __shared__ bf16_t Bs[128 * LDT];
  const int tid = threadIdx.x;
  const int m0 = blockIdx.y * 128, n0 = blockIdx.x * 128;
  const int lane = tid & 63, wid = tid >> 6;
  const int wr = wid >> 1, wc = wid & 1;
  const int lr = lane & 15, lh = lane >> 4;
  f32x4 acc[4][4] = {};
  for (int k0 = 0; k0 < 1024; k0 += 32) {
#pragma unroll
    for (int i = 0; i < 2; ++i) {
      int f = tid + i * 256;
      int r = f >> 2, c = (f & 3) * 8;
      *(bf16x8*)&As[r * LDT + c] = *(const bf16x8*)&A[(size_t)(m0 + r) * 1024 + k0 + c];
      *(bf16x8*)&Bs[r * LDT + c] = *(const bf16x8*)&W[(size_t)(n0 + r) * 1024 + k0 + c];
    }
    __syncthreads();
    bf16x8 af[4], bw[4];
#pragma unroll
    for (int m = 0; m < 4; ++m)
      af[m] = *(const bf16x8*)&As[(wr * 64 + m * 16 + lr) * LDT + lh * 8];
#pragma unroll
    for (int n = 0; n < 4; ++n)
      bw[n] = *(const bf16x8*)&Bs[(wc * 64 + n * 16 + lr) * LDT + lh * 8];
#pragma unroll
    for (int m = 0; m < 4; ++m)
#pragma unroll
      for (int n = 0; n < 4; ++n)
        acc[m][n] = MFMA16(af[m], bw[n], acc[m][n], 0, 0, 0);
    __syncthreads();
  }
#pragma unroll
  for (int n = 0; n < 4; ++n) {
    const int col = n0 + wc * 64 + n * 16 + lr;
    const float bv_ = bias[col];
#pragma unroll
    for (int m = 0; m < 4; ++m) {
      const int row0 = m0 + wr * 64 + m * 16 + lh * 4;
#pragma unroll
      for (int r = 0; r < 4; ++r)
        Co[(size_t)(row0 + r) * E_N + col] = acc[m][n][r] + bv_;
    }
  }
}

// ---------------------------------------------------------------------------
// score4: scale + rel_bias + mask for 4 consecutive k at (qrow, kc..kc+3)
// ---------------------------------------------------------------------------
static __device__ __forceinline__ f32x4 score4(
    f32x4 acc, int qrow, int kc, const unsigned char* __restrict__ mrow,
    const float* __restrict__ rbh, float rb_lo, float rb_hi)
{
  const int d0 = kc - qrow;
  float b0, b1, b2, b3;
  if (d0 >= 8) { b0 = b1 = b2 = b3 = rb_hi; }
  else if (d0 <= -11) { b0 = b1 = b2 = b3 = rb_lo; }
  else {
    int dd;
    dd = d0;     dd = dd < -8 ? -8 : (dd > 8 ? 8 : dd); b0 = rbh[dd + 8];
    dd = d0 + 1; dd = dd < -8 ? -8 : (dd > 8 ? 8 : dd); b1 = rbh[dd + 8];
    dd = d0 + 2; dd = dd < -8 ? -8 : (dd > 8 ? 8 : dd); b2 = rbh[dd + 8];
    dd = d0 + 3; dd = dd < -8 ? -8 : (dd > 8 ? 8 : dd); b3 = rbh[dd + 8];
  }
  const unsigned int mw = *(const unsigned int*)(mrow + kc);
  const float NEG = -__builtin_inff();
  f32x4 s;
  s[0] = (mw & 0xffu)       ? NEG : acc[0] * 0.125f + b0;
  s[1] = (mw & 0xff00u)     ? NEG : acc[1] * 0.125f + b1;
  s[2] = (mw & 0xff0000u)   ? NEG : acc[2] * 0.125f + b2;
  s[3] = (mw & 0xff000000u) ? NEG : acc[3] * 0.125f + b3;
  return s;
}

// ---------------------------------------------------------------------------
// Fused attention, LDS-staged K/V (flash structure).
// Block = 256 thr = 4 waves, 64 q-rows of one (b,h); wave w owns rows
// [q0+16w, +16) over the FULL k-sweep (no split-K -> no merges).
// K/V tiles (64 k) staged in LDS with XOR swizzle (granule ^= row&7,
// granule = 16B): staging writes and frag reads both at native b128 rate.
// P1: per 64-k tile {stage K, mfma(K,Q), score4 -> scores fp32, online m/s}.
// P2: per tile {stage K+V, recompute s (bit-identical), p -> attn fp32,
//     p->bf16 via per-wave LDS bounce -> PV MFMA vs LDS V-tile}.
// ---------------------------------------------------------------------------
__global__ __launch_bounds__(256) void fused_attn(
    const bf16_t* __restrict__ Q, const bf16_t* __restrict__ K,
    const bf16_t* __restrict__ Vt,
    const unsigned char* __restrict__ mask, const float* __restrict__ rel_bias,
    float* __restrict__ scores, float* __restrict__ attn, bf16_t* __restrict__ ctx)
{
  __shared__ bf16_t Ktile[64 * 64];            // 8KB  (64 k-rows x 64 d)
  __shared__ bf16_t Vtile[64 * 64];            // 8KB  (64 d-rows x 64 s)
  __shared__ bf16_t P_lds[4][16 * 132];        // 16.9KB per-wave P bounce

  const int bh = blockIdx.y, b = bh >> 4, h = bh & 15;
  const int q0 = blockIdx.x * 64;
  const int tid = threadIdx.x;
  const int w = tid >> 6, lane = tid & 63;
  const int lr = lane & 15, lh = lane >> 4;
  const int qrow = q0 + w * 16 + lr;

  const bf16_t* Qh = Q + (size_t)bh * (S_N * D_N);
  const bf16_t* Kh = K + (size_t)bh * (S_N * D_N);
  const bf16_t* Vh = Vt + (size_t)bh * (D_N * S_N);
  const unsigned char* mrow = mask + (size_t)b * S_N * S_N + (size_t)qrow * S_N;
  float* Srow = scores + (size_t)bh * S_N * S_N + (size_t)qrow * S_N;
  float* Arow = attn + (size_t)bh * S_N * S_N + (size_t)qrow * S_N;
  const float* rbh = rel_bias + h * 17;
  const float rb_lo = rbh[0], rb_hi = rbh[16];
  const float NEG = -__builtin_inff();

  // staging coords for this thread (granule = 8 bf16 = 16B; 8 granules/row)
  const int sg_row0 = tid >> 3, sg_c = tid & 7;          // granule tid
  const int sg_row1 = (tid + 256) >> 3;                  // granule tid+256
  const int sg_s0 = (sg_c ^ (sg_row0 & 7)) * 8;          // swizzled elem offs
  const int sg_s1 = (sg_c ^ (sg_row1 & 7)) * 8;

  // Q fragment for q-row qrow (held entire kernel)
  bf16x8 qa0 = *(const bf16x8*)&Qh[(size_t)qrow * D_N + lh * 8];
  bf16x8 qa1 = *(const bf16x8*)&Qh[(size_t)qrow * D_N + 32 + lh * 8];

  // frag-read swizzled offsets (row t*16+lr -> row&7 == lr&7)
  const int ks0 = (lh ^ (lr & 7)) * 8;                   // ka0 granule
  const int ks1 = ((4 + lh) ^ (lr & 7)) * 8;             // ka1 granule

  // ---- P1: scores + online (max,sum), full k-sweep -------------------------
  float mrun = NEG, srun = 0.f;
  for (int kt = 0; kt < 16; ++kt) {
    const int kb = kt * 64;
    __syncthreads();
    *(bf16x8*)&Ktile[sg_row0 * 64 + sg_s0] =
        *(const bf16x8*)&Kh[(size_t)(kb + sg_row0) * D_N + sg_c * 8];
    *(bf16x8*)&Ktile[sg_row1 * 64 + sg_s1] =
        *(const bf16x8*)&Kh[(size_t)(kb + sg_row1) * D_N + sg_c * 8];
    __syncthreads();
#pragma unroll
    for (int t = 0; t < 4; ++t) {
      const int krow = t * 16 + lr;
      bf16x8 ka0 = *(const bf16x8*)&Ktile[krow * 64 + ks0];
      bf16x8 ka1 = *(const bf16x8*)&Ktile[krow * 64 + ks1];
      f32x4 acc = {};
      acc = MFMA16(ka0, qa0, acc, 0, 0, 0);    // D[k][q]
      acc = MFMA16(ka1, qa1, acc, 0, 0, 0);
      const int kc = kb + t * 16 + 4 * lh;
      f32x4 s = score4(acc, qrow, kc, mrow, rbh, rb_lo, rb_hi);
      *(f32x4*)&Srow[kc] = s;
      const float mt = fmaxf(fmaxf(s[0], s[1]), fmaxf(s[2], s[3]));
      const float mn = fmaxf(mrun, mt);
      if (mn > NEG) {
        srun = srun * __expf(mrun - mn)
             + __expf(s[0] - mn) + __expf(s[1] - mn)
             + __expf(s[2] - mn) + __expf(s[3] - mn);
        mrun = mn;
      }
    }
  }
  // combine across the 4 lanes sharing this q-row (lane^16, lane^32)
#pragma unroll
  for (int off = 16; off <= 32; off <<= 1) {
    const float m2 = __shfl_xor(mrun, off);
    const float s2 = __shfl_xor(srun, off);
    const float mn = fmaxf(mrun, m2);
    if (mn > NEG) {
      srun = srun * __expf(mrun - mn) + s2 * __expf(m2 - mn);
      mrun = mn;
    }
  }
  const float M = mrun;
  const float invs = 1.0f / srun;

  // ---- P2: recompute (L2-hot restage), attn write, PV ----------------------
  bf16_t* Pw = P_lds[w];
  f32x4 accp[4] = {};
  for (int kt = 0; kt < 16; ++kt) {
    const int kb = kt * 64;
    __syncthreads();
    *(bf16x8*)&Ktile[sg_row0 * 64 + sg_s0] =
        *(const bf16x8*)&Kh[(size_t)(kb + sg_row0) * D_N + sg_c * 8];
    *(bf16x8*)&Ktile[sg_row1 * 64 + sg_s1] =
        *(const bf16x8*)&Kh[(size_t)(kb + sg_row1) * D_N + sg_c * 8];
    *(bf16x8*)&Vtile[sg_row0 * 64 + sg_s0] =
        *(const bf16x8*)&Vh[(size_t)sg_row0 * S_N + kb + sg_c * 8];
    *(bf16x8*)&Vtile[sg_row1 * 64 + sg_s1] =
        *(const bf16x8*)&Vh[(size_t)sg_row1 * S_N + kb + sg_c * 8];
    __syncthreads();
#pragma unroll
    for (int t = 0; t < 4; ++t) {
      const int krow = t * 16 + lr;
      bf16x8 ka0 = *(const bf16x8*)&Ktile[krow * 64 + ks0];
      bf16x8 ka1 = *(const bf16x8*)&Ktile[krow * 64 + ks1];
      f32x4 acc = {};
      acc = MFMA16(ka0, qa0, acc, 0, 0, 0);
      acc = MFMA16(ka1, qa1, acc, 0, 0, 0);
      const int kc = kb + t * 16 + 4 * lh;
      f32x4 s = score4(acc, qrow, kc, mrow, rbh, rb_lo, rb_hi);
      f32x4 p; bf16x4 pb;
#pragma unroll
      for (int j = 0; j < 4; ++j) {
        p[j] = __expf(s[j] - M) * invs;
        pb[j] = f2b(p[j]);
      }
      *(f32x4*)&Arow[kc] = p;
      *(bf16x4*)&Pw[lr * 132 + t * 16 + 4 * lh] = pb;
    }
    // PV for this 64-k tile
#pragma unroll
    for (int ch = 0; ch < 2; ++ch) {
      bf16x8 pa = *(const bf16x8*)&Pw[lr * 132 + ch * 32 + lh * 8];
#pragma unroll
      for (int dt = 0; dt < 4; ++dt) {
        const int drow = dt * 16 + lr;
        bf16x8 vb = *(const bf16x8*)&Vtile[drow * 64 + (((ch * 4 + lh) ^ (lr & 7)) * 8)];
        accp[dt] = MFMA16(pa, vb, accp[dt], 0, 0, 0);    // D[q][d]
      }
    }
  }
  // ctx epilogue: lane holds q = q0+16w+4lh+r, d = dt*16+lr
#pragma unroll
  for (int dt = 0; dt < 4; ++dt)
#pragma unroll
    for (int r = 0; r < 4; ++r)
      ctx[((size_t)(b * S_N + q0 + w * 16 + 4 * lh + r)) * E_N + h * 64 + dt * 16 + lr] =
          f2b(accp[dt][r]);
}

// ---------------------------------------------------------------------------
extern "C" void kernel_launch(void* const* d_in, const int* in_sizes, int n_in,
                              void* d_out, int out_size, void* d_ws, size_t ws_size,
                              hipStream_t stream) {
  (void)in_sizes; (void)n_in; (void)out_size; (void)ws_size;
  const float* query = (const float*)d_in[0];
  const float* key   = (const float*)d_in[1];
  const float* value = (const float*)d_in[2];
  const unsigned char* mask = (const unsigned char*)d_in[3];
  const float* Wq = (const float*)d_in[4];
  const float* bq = (const float*)d_in[5];
  const float* Wk = (const float*)d_in[6];
  const float* bk = (const float*)d_in[7];
  const float* Wv = (const float*)d_in[8];
  const float* bv = (const float*)d_in[9];
  const float* Wo = (const float*)d_in[10];
  const float* bo = (const float*)d_in[11];
  const float* rel_bias = (const float*)d_in[12];

  float* out_f    = (float*)d_out;                     //  4,194,304 floats
  float* attn_f   = out_f + (size_t)4194304;           // 67,108,864 floats
  float* scores_f = attn_f + (size_t)67108864;         // 67,108,864 floats

  char* ws = (char*)d_ws;                              // ~2GiB available; 64MB used
  bf16_t* qbf  = (bf16_t*)(ws);                        // (4096,1024) 8MB
  bf16_t* kbf  = (bf16_t*)(ws + (8ull  << 20));        // 8MB
  bf16_t* vbf  = (bf16_t*)(ws + (16ull << 20));        // 8MB
  bf16_t* Wqb  = (bf16_t*)(ws + (24ull << 20));        // 2MB
  bf16_t* Wkb  = (bf16_t*)(ws + (26ull << 20));        // 2MB
  bf16_t* Wvb  = (bf16_t*)(ws + (28ull << 20));        // 2MB
  bf16_t* Wob  = (bf16_t*)(ws + (30ull << 20));        // 2MB
  bf16_t* Qbf  = (bf16_t*)(ws + (32ull << 20));        // (B,H,S,D) 8MB
  bf16_t* Kbf  = (bf16_t*)(ws + (40ull << 20));        // (B,H,S,D) 8MB
  bf16_t* Vtbf = (bf16_t*)(ws + (48ull << 20));        // (B,H,D,S) 8MB
  bf16_t* CTX  = (bf16_t*)(ws + (56ull << 20));        // (B,S,E)   8MB

  convert_kernel<<<dim3(8192), dim3(256), 0, stream>>>(
      query, key, value, Wq, Wk, Wv, Wo, qbf, kbf, vbf, Wqb, Wkb, Wvb, Wob);
  qkv_gemm<<<dim3(8, 32, 3), dim3(256), 0, stream>>>(
      qbf, kbf, vbf, Wqb, Wkb, Wvb, bq, bk, bv, Qbf, Kbf, Vtbf);
  fused_attn<<<dim3(16, 64), dim3(256), 0, stream>>>(
      Qbf, Kbf, Vtbf, mask, rel_bias, scores_f, attn_f, CTX);
  out_gemm<<<dim3(8, 32), dim3(256), 0, stream>>>(CTX, Wob, bo, out_f);
}

// Round 9
// 256.434 us; speedup vs baseline: 2.2606x; 1.4670x over previous
//
#include <hip/hip_runtime.h>

typedef __bf16 bf16_t;
typedef bf16_t bf16x4 __attribute__((ext_vector_type(4)));
typedef bf16_t bf16x8 __attribute__((ext_vector_type(8)));
typedef float f32x4 __attribute__((ext_vector_type(4)));
typedef float f32x8 __attribute__((ext_vector_type(8)));

#define B_N 4
#define S_N 1024
#define E_N 1024
#define H_N 16
#define D_N 64

#define MFMA16 __builtin_amdgcn_mfma_f32_16x16x32_bf16

static __device__ __forceinline__ bf16_t f2b(float x) { return (bf16_t)x; }

// ---------------------------------------------------------------------------
// One-shot fp32 -> bf16 conversion of q,k,v and the four weight matrices.
// ---------------------------------------------------------------------------
__global__ __launch_bounds__(256) void convert_kernel(
    const float* __restrict__ q, const float* __restrict__ k, const float* __restrict__ v,
    const float* __restrict__ wq, const float* __restrict__ wk,
    const float* __restrict__ wv, const float* __restrict__ wo,
    bf16_t* __restrict__ dq, bf16_t* __restrict__ dk, bf16_t* __restrict__ dv,
    bf16_t* __restrict__ dwq, bf16_t* __restrict__ dwk,
    bf16_t* __restrict__ dwv, bf16_t* __restrict__ dwo)
{
  const size_t e = ((size_t)blockIdx.x * 256 + threadIdx.x) * 8;
  const float* src; bf16_t* dst; size_t off;
  if (e < 12582912ull) {                       // q | k | v (4M elems each)
    const int which = (int)(e >> 22);
    off = e & 4194303ull;
    src = which == 0 ? q : (which == 1 ? k : v);
    dst = which == 0 ? dq : (which == 1 ? dk : dv);
  } else {                                     // Wq | Wk | Wv | Wo (1M each)
    const size_t e2 = e - 12582912ull;
    const int which = (int)(e2 >> 20);
    off = e2 & 1048575ull;
    src = which == 0 ? wq : (which == 1 ? wk : (which == 2 ? wv : wo));
    dst = which == 0 ? dwq : (which == 1 ? dwk : (which == 2 ? dwv : dwo));
  }
  f32x8 x = *(const f32x8*)(src + off);
  bf16x8 r;
#pragma unroll
  for (int i = 0; i < 8; ++i) r[i] = f2b(x[i]);
  *(bf16x8*)(dst + off) = r;
}

// ---------------------------------------------------------------------------
// mask row-any precompute: flags[row] = any(mask[row][*]) for the 4096 rows.
// One wave per 1024-byte row, fully coalesced.
// ---------------------------------------------------------------------------
__global__ __launch_bounds__(256) void mask_rowany(
    const unsigned char* __restrict__ mask, unsigned char* __restrict__ flags)
{
  const int row = blockIdx.x * 4 + (threadIdx.x >> 6);
  const int lane = threadIdx.x & 63;
  const uint4 v = *(const uint4*)(mask + (size_t)row * 1024 + lane * 16);
  const unsigned int any = v.x | v.y | v.z | v.w;
  const unsigned long long bal = __ballot(any != 0);
  if (lane == 0) flags[row] = bal ? 1 : 0;
}

// ---------------------------------------------------------------------------
// Batched QKV projection GEMM: z selects (A, W, bias, output layout).
// ---------------------------------------------------------------------------
__global__ __launch_bounds__(256) void qkv_gemm(
    const bf16_t* __restrict__ qA, const bf16_t* __restrict__ kA, const bf16_t* __restrict__ vA,
    const bf16_t* __restrict__ Wq, const bf16_t* __restrict__ Wk, const bf16_t* __restrict__ Wv,
    const float* __restrict__ bq, const float* __restrict__ bk, const float* __restrict__ bv,
    bf16_t* __restrict__ Qo, bf16_t* __restrict__ Ko, bf16_t* __restrict__ Vto)
{
  const int z = blockIdx.z;
  const bf16_t* A = z == 0 ? qA : (z == 1 ? kA : vA);
  const bf16_t* W = z == 0 ? Wq : (z == 1 ? Wk : Wv);
  const float* bias = z == 0 ? bq : (z == 1 ? bk : bv);

  constexpr int LDT = 40;
  __shared__ bf16_t As[128 * LDT];
  __shared__ bf16_t Bs[128 * LDT];
  const int tid = threadIdx.x;
  const int m0 = blockIdx.y * 128, n0 = blockIdx.x * 128;
  const int lane = tid & 63, wid = tid >> 6;
  const int wr = wid >> 1, wc = wid & 1;
  const int lr = lane & 15, lh = lane >> 4;
  f32x4 acc[4][4] = {};
  for (int k0 = 0; k0 < 1024; k0 += 32) {
#pragma unroll
    for (int i = 0; i < 2; ++i) {
      int f = tid + i * 256;
      int r = f >> 2, c = (f & 3) * 8;
      *(bf16x8*)&As[r * LDT + c] = *(const bf16x8*)&A[(size_t)(m0 + r) * 1024 + k0 + c];
      *(bf16x8*)&Bs[r * LDT + c] = *(const bf16x8*)&W[(size_t)(n0 + r) * 1024 + k0 + c];
    }
    __syncthreads();
    bf16x8 af[4], bw[4];
#pragma unroll
    for (int m = 0; m < 4; ++m)
      af[m] = *(const bf16x8*)&As[(wr * 64 + m * 16 + lr) * LDT + lh * 8];
#pragma unroll
    for (int n = 0; n < 4; ++n)
      bw[n] = *(const bf16x8*)&Bs[(wc * 64 + n * 16 + lr) * LDT + lh * 8];
#pragma unroll
    for (int m = 0; m < 4; ++m)
#pragma unroll
      for (int n = 0; n < 4; ++n)
        acc[m][n] = MFMA16(af[m], bw[n], acc[m][n], 0, 0, 0);
    __syncthreads();
  }
#pragma unroll
  for (int n = 0; n < 4; ++n) {
    const int col = n0 + wc * 64 + n * 16 + lr;
    const float bv_ = bias[col];
    const int h = col >> 6, d = col & 63;
#pragma unroll
    for (int m = 0; m < 4; ++m) {
      const int row0 = m0 + wr * 64 + m * 16 + lh * 4;
#pragma unroll
      for (int r = 0; r < 4; ++r) {
        const int row = row0 + r;
        const float v = acc[m][n][r] + bv_;
        const int b = row >> 10, s = row & 1023;
        if (z == 0)
          Qo[((size_t)(b * H_N + h) * S_N + s) * D_N + d] = f2b(v);
        else if (z == 1)
          Ko[((size_t)(b * H_N + h) * S_N + s) * D_N + d] = f2b(v);
        else
          Vto[((size_t)(b * H_N + h) * D_N + d) * S_N + s] = f2b(v);
      }
    }
  }
}

// ---------------------------------------------------------------------------
// Output projection: fp32 out.
// ---------------------------------------------------------------------------
__global__ __launch_bounds__(256) void out_gemm(
    const bf16_t* __restrict__ A, const bf16_t* __restrict__ W,
    const float* __restrict__ bias, float* __restrict__ Co)
{
  constexpr int LDT = 40;
  __shared__ bf16_t As[128 * LDT];
  __shared__ bf16_t Bs[128 * LDT];
  const int tid = threadIdx.x;
  const int m0 = blockIdx.y * 128, n0 = blockIdx.x * 128;
  const int lane = tid & 63, wid = tid >> 6;
  const int wr = wid >> 1, wc = wid & 1;
  const int lr = lane & 15, lh = lane >> 4;
  f32x4 acc[4][4] = {};
  for (int k0 = 0; k0 < 1024; k0 += 32) {
#pragma unroll
    for (int i = 0; i < 2; ++i) {
      int f = tid + i * 256;
      int r = f >> 2, c = (f & 3) * 8;
      *(bf16x8*)&As[r * LDT + c] = *(const bf16x8*)&A[(size_t)(m0 + r) * 1024 + k0 + c];
      *(bf16x8*)&Bs[r * LDT + c] = *(const bf16x8*)&W[(size_t)(n0 + r) * 1024 + k0 + c];
    }
    __syncthreads();
    bf16x8 af[4], bw[4];
#pragma unroll
    for (int m = 0; m < 4; ++m)
      af[m] = *(const bf16x8*)&As[(wr * 64 + m * 16 + lr) * LDT + lh * 8];
#pragma unroll
    for (int n = 0; n < 4; ++n)
      bw[n] = *(const bf16x8*)&Bs[(wc * 64 + n * 16 + lr) * LDT + lh * 8];
#pragma unroll
    for (int m = 0; m < 4; ++m)
#pragma unroll
      for (int n = 0; n < 4; ++n)
        acc[m][n] = MFMA16(af[m], bw[n], acc[m][n], 0, 0, 0);
    __syncthreads();
  }
#pragma unroll
  for (int n = 0; n < 4; ++n) {
    const int col = n0 + wc * 64 + n * 16 + lr;
    const float bv_ = bias[col];
#pragma unroll
    for (int m = 0; m < 4; ++m) {
      const int row0 = m0 + wr * 64 + m * 16 + lh * 4;
#pragma unroll
      for (int r = 0; r < 4; ++r)
        Co[(size_t)(row0 + r) * E_N + col] = acc[m][n][r] + bv_;
    }
  }
}

// ---------------------------------------------------------------------------
// score4: scale + rel_bias (+ mask only if um) for 4 consecutive k.
// ---------------------------------------------------------------------------
static __device__ __forceinline__ f32x4 score4(
    f32x4 acc, int qrow, int kc, const unsigned char* __restrict__ mrow,
    const float* __restrict__ rbh, float rb_lo, float rb_hi, bool um)
{
  const int d0 = kc - qrow;
  float b0, b1, b2, b3;
  if (d0 >= 8) { b0 = b1 = b2 = b3 = rb_hi; }
  else if (d0 <= -11) { b0 = b1 = b2 = b3 = rb_lo; }
  else {
    int dd;
    dd = d0;     dd = dd < -8 ? -8 : (dd > 8 ? 8 : dd); b0 = rbh[dd + 8];
    dd = d0 + 1; dd = dd < -8 ? -8 : (dd > 8 ? 8 : dd); b1 = rbh[dd + 8];
    dd = d0 + 2; dd = dd < -8 ? -8 : (dd > 8 ? 8 : dd); b2 = rbh[dd + 8];
    dd = d0 + 3; dd = dd < -8 ? -8 : (dd > 8 ? 8 : dd); b3 = rbh[dd + 8];
  }
  f32x4 s;
  s[0] = acc[0] * 0.125f + b0;
  s[1] = acc[1] * 0.125f + b1;
  s[2] = acc[2] * 0.125f + b2;
  s[3] = acc[3] * 0.125f + b3;
  if (um) {                                    // rare path: per-element mask
    const unsigned int mw = *(const unsigned int*)(mrow + kc);
    const float NEG = -__builtin_inff();
    if (mw & 0xffu)       s[0] = NEG;
    if (mw & 0xff00u)     s[1] = NEG;
    if (mw & 0xff0000u)   s[2] = NEG;
    if (mw & 0xff000000u) s[3] = NEG;
  }
  return s;
}

// ---------------------------------------------------------------------------
// Fused attention, LDS-staged K/V + LDS-transposed coalesced score writes.
// Block = 4 waves, 64 q-rows of one (b,h); wave w owns rows [q0+16w,+16).
// Per 64-k tile: stage K (V in P2) with XOR swizzle; mfma(K,Q) swapped;
// score tile goes MFMA-layout -> per-wave S_lds[16][68] -> 4 coalesced
// 256B-per-row global writes (full cache lines). Mask handled via per-row
// any-flags (all-false rows skip mask loads entirely). P2 recomputes s
// bit-identically, stores p to S_lds, writes attn coalesced, and reads the
// same tile back as bf16 PV A-fragments (old P_lds bounce eliminated).
// ---------------------------------------------------------------------------
__global__ __launch_bounds__(256) void fused_attn(
    const bf16_t* __restrict__ Q, const bf16_t* __restrict__ K,
    const bf16_t* __restrict__ Vt,
    const unsigned char* __restrict__ mask, const unsigned char* __restrict__ rowflag,
    const float* __restrict__ rel_bias,
    float* __restrict__ scores, float* __restrict__ attn, bf16_t* __restrict__ ctx)
{
  __shared__ bf16_t Ktile[64 * 64];            // 8KB
  __shared__ bf16_t Vtile[64 * 64];            // 8KB
  __shared__ float S_lds[4][16][68];           // 17KB per-wave transpose tile

  const int bh = blockIdx.y, b = bh >> 4, h = bh & 15;
  const int q0 = blockIdx.x * 64;
  const int tid = threadIdx.x;
  const int w = tid >> 6, lane = tid & 63;
  const int lr = lane & 15, lh = lane >> 4;
  const int qrow = q0 + w * 16 + lr;

  const bf16_t* Qh = Q + (size_t)bh * (S_N * D_N);
  const bf16_t* Kh = K + (size_t)bh * (S_N * D_N);
  const bf16_t* Vh = Vt + (size_t)bh * (D_N * S_N);
  const unsigned char* mrow = mask + (size_t)b * S_N * S_N + (size_t)qrow * S_N;
  float* Sbase = scores + (size_t)bh * S_N * S_N + (size_t)(q0 + w * 16) * S_N;
  float* Abase = attn + (size_t)bh * S_N * S_N + (size_t)(q0 + w * 16) * S_N;
  const float* rbh = rel_bias + h * 17;
  const float rb_lo = rbh[0], rb_hi = rbh[16];
  const float NEG = -__builtin_inff();
  const bool um = rowflag[b * S_N + qrow] != 0;

  // staging coords (granule = 8 bf16 = 16B; 8 granules/row; XOR swizzle)
  const int sg_row0 = tid >> 3, sg_c = tid & 7;
  const int sg_row1 = (tid + 256) >> 3;
  const int sg_s0 = (sg_c ^ (sg_row0 & 7)) * 8;
  const int sg_s1 = (sg_c ^ (sg_row1 & 7)) * 8;

  // Q fragment (held entire kernel)
  bf16x8 qa0 = *(const bf16x8*)&Qh[(size_t)qrow * D_N + lh * 8];
  bf16x8 qa1 = *(const bf16x8*)&Qh[(size_t)qrow * D_N + 32 + lh * 8];

  const int ks0 = (lh ^ (lr & 7)) * 8;
  const int ks1 = ((4 + lh) ^ (lr & 7)) * 8;

  // ---- P1: scores + online (max,sum) --------------------------------------
  float mrun = NEG, srun = 0.f;
  for (int kt = 0; kt < 16; ++kt) {
    const int kb = kt * 64;
    __syncthreads();
    *(bf16x8*)&Ktile[sg_row0 * 64 + sg_s0] =
        *(const bf16x8*)&Kh[(size_t)(kb + sg_row0) * D_N + sg_c * 8];
    *(bf16x8*)&Ktile[sg_row1 * 64 + sg_s1] =
        *(const bf16x8*)&Kh[(size_t)(kb + sg_row1) * D_N + sg_c * 8];
    __syncthreads();
#pragma unroll
    for (int t = 0; t < 4; ++t) {
      const int krow = t * 16 + lr;
      bf16x8 ka0 = *(const bf16x8*)&Ktile[krow * 64 + ks0];
      bf16x8 ka1 = *(const bf16x8*)&Ktile[krow * 64 + ks1];
      f32x4 acc = {};
      acc = MFMA16(ka0, qa0, acc, 0, 0, 0);    // D[k][q]
      acc = MFMA16(ka1, qa1, acc, 0, 0, 0);
      const int kc = kb + t * 16 + 4 * lh;
      f32x4 s = score4(acc, qrow, kc, mrow, rbh, rb_lo, rb_hi, um);
      *(f32x4*)&S_lds[w][lr][t * 16 + 4 * lh] = s;
      const float mt = fmaxf(fmaxf(s[0], s[1]), fmaxf(s[2], s[3]));
      const float mn = fmaxf(mrun, mt);
      if (mn > NEG) {
        srun = srun * __expf(mrun - mn)
             + __expf(s[0] - mn) + __expf(s[1] - mn)
             + __expf(s[2] - mn) + __expf(s[3] - mn);
        mrun = mn;
      }
    }
    // coalesced store: 4 instrs, each 4 rows x 256B full-line segments
#pragma unroll
    for (int i = 0; i < 4; ++i) {
      const int row = 4 * i + lh;
      f32x4 sv = *(const f32x4*)&S_lds[w][row][lr * 4];
      *(f32x4*)&Sbase[(size_t)row * S_N + kb + lr * 4] = sv;
    }
  }
  // combine across the 4 lanes sharing this q-row
#pragma unroll
  for (int off = 16; off <= 32; off <<= 1) {
    const float m2 = __shfl_xor(mrun, off);
    const float s2 = __shfl_xor(srun, off);
    const float mn = fmaxf(mrun, m2);
    if (mn > NEG) {
      srun = srun * __expf(mrun - mn) + s2 * __expf(m2 - mn);
      mrun = mn;
    }
  }
  const float M = mrun;
  const float invs = 1.0f / srun;

  // ---- P2: recompute, attn write (coalesced), PV ---------------------------
  f32x4 accp[4] = {};
  for (int kt = 0; kt < 16; ++kt) {
    const int kb = kt * 64;
    __syncthreads();
    *(bf16x8*)&Ktile[sg_row0 * 64 + sg_s0] =
        *(const bf16x8*)&Kh[(size_t)(kb + sg_row0) * D_N + sg_c * 8];
    *(bf16x8*)&Ktile[sg_row1 * 64 + sg_s1] =
        *(const bf16x8*)&Kh[(size_t)(kb + sg_row1) * D_N + sg_c * 8];
    *(bf16x8*)&Vtile[sg_row0 * 64 + sg_s0] =
        *(const bf16x8*)&Vh[(size_t)sg_row0 * S_N + kb + sg_c * 8];
    *(bf16x8*)&Vtile[sg_row1 * 64 + sg_s1] =
        *(const bf16x8*)&Vh[(size_t)sg_row1 * S_N + kb + sg_c * 8];
    __syncthreads();
#pragma unroll
    for (int t = 0; t < 4; ++t) {
      const int krow = t * 16 + lr;
      bf16x8 ka0 = *(const bf16x8*)&Ktile[krow * 64 + ks0];
      bf16x8 ka1 = *(const bf16x8*)&Ktile[krow * 64 + ks1];
      f32x4 acc = {};
      acc = MFMA16(ka0, qa0, acc, 0, 0, 0);
      acc = MFMA16(ka1, qa1, acc, 0, 0, 0);
      const int kc = kb + t * 16 + 4 * lh;
      f32x4 s = score4(acc, qrow, kc, mrow, rbh, rb_lo, rb_hi, um);
      f32x4 p;
#pragma unroll
      for (int j = 0; j < 4; ++j) p[j] = __expf(s[j] - M) * invs;
      *(f32x4*)&S_lds[w][lr][t * 16 + 4 * lh] = p;
    }
    // coalesced attn store
#pragma unroll
    for (int i = 0; i < 4; ++i) {
      const int row = 4 * i + lh;
      f32x4 pv = *(const f32x4*)&S_lds[w][row][lr * 4];
      *(f32x4*)&Abase[(size_t)row * S_N + kb + lr * 4] = pv;
    }
    // PV: A-frags from S_lds (row lr, k = ch*32 + lh*8 + j)
#pragma unroll
    for (int ch = 0; ch < 2; ++ch) {
      f32x8 pf = *(const f32x8*)&S_lds[w][lr][ch * 32 + lh * 8];
      bf16x8 pa;
#pragma unroll
      for (int j = 0; j < 8; ++j) pa[j] = f2b(pf[j]);
#pragma unroll
      for (int dt = 0; dt < 4; ++dt) {
        const int drow = dt * 16 + lr;
        bf16x8 vb = *(const bf16x8*)&Vtile[drow * 64 + (((ch * 4 + lh) ^ (lr & 7)) * 8)];
        accp[dt] = MFMA16(pa, vb, accp[dt], 0, 0, 0);    // D[q][d]
      }
    }
  }
  // ctx epilogue
#pragma unroll
  for (int dt = 0; dt < 4; ++dt)
#pragma unroll
    for (int r = 0; r < 4; ++r)
      ctx[((size_t)(b * S_N + q0 + w * 16 + 4 * lh + r)) * E_N + h * 64 + dt * 16 + lr] =
          f2b(accp[dt][r]);
}

// ---------------------------------------------------------------------------
extern "C" void kernel_launch(void* const* d_in, const int* in_sizes, int n_in,
                              void* d_out, int out_size, void* d_ws, size_t ws_size,
                              hipStream_t stream) {
  (void)in_sizes; (void)n_in; (void)out_size; (void)ws_size;
  const float* query = (const float*)d_in[0];
  const float* key   = (const float*)d_in[1];
  const float* value = (const float*)d_in[2];
  const unsigned char* mask = (const unsigned char*)d_in[3];
  const float* Wq = (const float*)d_in[4];
  const float* bq = (const float*)d_in[5];
  const float* Wk = (const float*)d_in[6];
  const float* bk = (const float*)d_in[7];
  const float* Wv = (const float*)d_in[8];
  const float* bv = (const float*)d_in[9];
  const float* Wo = (const float*)d_in[10];
  const float* bo = (const float*)d_in[11];
  const float* rel_bias = (const float*)d_in[12];

  float* out_f    = (float*)d_out;                     //  4,194,304 floats
  float* attn_f   = out_f + (size_t)4194304;           // 67,108,864 floats
  float* scores_f = attn_f + (size_t)67108864;         // 67,108,864 floats

  char* ws = (char*)d_ws;                              // ~2GiB; 65MB used
  bf16_t* qbf  = (bf16_t*)(ws);                        // (4096,1024) 8MB
  bf16_t* kbf  = (bf16_t*)(ws + (8ull  << 20));        // 8MB
  bf16_t* vbf  = (bf16_t*)(ws + (16ull << 20));        // 8MB
  bf16_t* Wqb  = (bf16_t*)(ws + (24ull << 20));        // 2MB
  bf16_t* Wkb  = (bf16_t*)(ws + (26ull << 20));        // 2MB
  bf16_t* Wvb  = (bf16_t*)(ws + (28ull << 20));        // 2MB
  bf16_t* Wob  = (bf16_t*)(ws + (30ull << 20));        // 2MB
  bf16_t* Qbf  = (bf16_t*)(ws + (32ull << 20));        // (B,H,S,D) 8MB
  bf16_t* Kbf  = (bf16_t*)(ws + (40ull << 20));        // (B,H,S,D) 8MB
  bf16_t* Vtbf = (bf16_t*)(ws + (48ull << 20));        // (B,H,D,S) 8MB
  bf16_t* CTX  = (bf16_t*)(ws + (56ull << 20));        // (B,S,E)   8MB
  unsigned char* FLAGS = (unsigned char*)(ws + (64ull << 20)); // 4KB

  convert_kernel<<<dim3(8192), dim3(256), 0, stream>>>(
      query, key, value, Wq, Wk, Wv, Wo, qbf, kbf, vbf, Wqb, Wkb, Wvb, Wob);
  mask_rowany<<<dim3(1024), dim3(256), 0, stream>>>(mask, FLAGS);
  qkv_gemm<<<dim3(8, 32, 3), dim3(256), 0, stream>>>(
      qbf, kbf, vbf, Wqb, Wkb, Wvb, bq, bk, bv, Qbf, Kbf, Vtbf);
  fused_attn<<<dim3(16, 64), dim3(256), 0, stream>>>(
      Qbf, Kbf, Vtbf, mask, FLAGS, rel_bias, scores_f, attn_f, CTX);
  out_gemm<<<dim3(8, 32), dim3(256), 0, stream>>>(CTX, Wob, bo, out_f);
}

// Round 10
// 241.624 us; speedup vs baseline: 2.3992x; 1.0613x over previous
//
#include <hip/hip_runtime.h>

typedef __bf16 bf16_t;
typedef bf16_t bf16x4 __attribute__((ext_vector_type(4)));
typedef bf16_t bf16x8 __attribute__((ext_vector_type(8)));
typedef float f32x4 __attribute__((ext_vector_type(4)));
typedef float f32x8 __attribute__((ext_vector_type(8)));

#define B_N 4
#define S_N 1024
#define E_N 1024
#define H_N 16
#define D_N 64

#define MFMA16 __builtin_amdgcn_mfma_f32_16x16x32_bf16

static __device__ __forceinline__ bf16_t f2b(float x) { return (bf16_t)x; }

// async global->LDS, 16B per lane; lds dest = wave-uniform base + lane*16
static __device__ __forceinline__ void gload_lds16(const void* g, void* l) {
  __builtin_amdgcn_global_load_lds(
      (const __attribute__((address_space(1))) unsigned int*)g,
      (__attribute__((address_space(3))) unsigned int*)l, 16, 0, 0);
}

// ---------------------------------------------------------------------------
// One-shot fp32 -> bf16 conversion of q,k,v and the four weight matrices.
// ---------------------------------------------------------------------------
__global__ __launch_bounds__(256) void convert_kernel(
    const float* __restrict__ q, const float* __restrict__ k, const float* __restrict__ v,
    const float* __restrict__ wq, const float* __restrict__ wk,
    const float* __restrict__ wv, const float* __restrict__ wo,
    bf16_t* __restrict__ dq, bf16_t* __restrict__ dk, bf16_t* __restrict__ dv,
    bf16_t* __restrict__ dwq, bf16_t* __restrict__ dwk,
    bf16_t* __restrict__ dwv, bf16_t* __restrict__ dwo)
{
  const size_t e = ((size_t)blockIdx.x * 256 + threadIdx.x) * 8;
  const float* src; bf16_t* dst; size_t off;
  if (e < 12582912ull) {                       // q | k | v (4M elems each)
    const int which = (int)(e >> 22);
    off = e & 4194303ull;
    src = which == 0 ? q : (which == 1 ? k : v);
    dst = which == 0 ? dq : (which == 1 ? dk : dv);
  } else {                                     // Wq | Wk | Wv | Wo (1M each)
    const size_t e2 = e - 12582912ull;
    const int which = (int)(e2 >> 20);
    off = e2 & 1048575ull;
    src = which == 0 ? wq : (which == 1 ? wk : (which == 2 ? wv : wo));
    dst = which == 0 ? dwq : (which == 1 ? dwk : (which == 2 ? dwv : dwo));
  }
  f32x8 x = *(const f32x8*)(src + off);
  bf16x8 r;
#pragma unroll
  for (int i = 0; i < 8; ++i) r[i] = f2b(x[i]);
  *(bf16x8*)(dst + off) = r;
}

// ---------------------------------------------------------------------------
// mask row-any precompute: flags[row] = any(mask[row][*]).
// ---------------------------------------------------------------------------
__global__ __launch_bounds__(256) void mask_rowany(
    const unsigned char* __restrict__ mask, unsigned char* __restrict__ flags)
{
  const int row = blockIdx.x * 4 + (threadIdx.x >> 6);
  const int lane = threadIdx.x & 63;
  const uint4 v = *(const uint4*)(mask + (size_t)row * 1024 + lane * 16);
  const unsigned int any = v.x | v.y | v.z | v.w;
  const unsigned long long bal = __ballot(any != 0);
  if (lane == 0) flags[row] = bal ? 1 : 0;
}

// ---------------------------------------------------------------------------
// Batched QKV projection GEMM, m97-style staging:
// global_load_lds 16B into linear LDS [128][32] (no pad), frag reads b128.
// z=0 -> Q (B,H,S,D); z=1 -> K (B,H,S,D); z=2 -> V^T (B,H,D,S).
// ---------------------------------------------------------------------------
__global__ __launch_bounds__(256) void qkv_gemm(
    const bf16_t* __restrict__ qA, const bf16_t* __restrict__ kA, const bf16_t* __restrict__ vA,
    const bf16_t* __restrict__ Wq, const bf16_t* __restrict__ Wk, const bf16_t* __restrict__ Wv,
    const float* __restrict__ bq, const float* __restrict__ bk, const float* __restrict__ bv,
    bf16_t* __restrict__ Qo, bf16_t* __restrict__ Ko, bf16_t* __restrict__ Vto)
{
  const int z = blockIdx.z;
  const bf16_t* A = z == 0 ? qA : (z == 1 ? kA : vA);
  const bf16_t* W = z == 0 ? Wq : (z == 1 ? Wk : Wv);
  const float* bias = z == 0 ? bq : (z == 1 ? bk : bv);

  __shared__ bf16_t As[128 * 32];              // 8KB linear
  __shared__ bf16_t Bs[128 * 32];              // 8KB linear
  const int tid = threadIdx.x;
  const int m0 = blockIdx.y * 128, n0 = blockIdx.x * 128;
  const int lane = tid & 63, wid = tid >> 6;
  const int wr = wid >> 1, wc = wid & 1;
  const int lr = lane & 15, lh = lane >> 4;
  const int sr = lane >> 2, sc = (lane & 3) * 8;   // staging row/col within 16-row group
  f32x4 acc[4][4] = {};
  for (int k0 = 0; k0 < 1024; k0 += 32) {
#pragma unroll
    for (int i = 0; i < 2; ++i) {                 // wave stages 2x16 rows of A and W
      const int br = wid * 32 + i * 16;
      gload_lds16(&A[(size_t)(m0 + br + sr) * 1024 + k0 + sc], &As[br * 32]);
      gload_lds16(&W[(size_t)(n0 + br + sr) * 1024 + k0 + sc], &Bs[br * 32]);
    }
    __syncthreads();
    bf16x8 af[4], bw[4];
#pragma unroll
    for (int m = 0; m < 4; ++m)
      af[m] = *(const bf16x8*)&As[(wr * 64 + m * 16 + lr) * 32 + lh * 8];
#pragma unroll
    for (int n = 0; n < 4; ++n)
      bw[n] = *(const bf16x8*)&Bs[(wc * 64 + n * 16 + lr) * 32 + lh * 8];
#pragma unroll
    for (int m = 0; m < 4; ++m)
#pragma unroll
      for (int n = 0; n < 4; ++n)
        acc[m][n] = MFMA16(af[m], bw[n], acc[m][n], 0, 0, 0);
    __syncthreads();
  }
#pragma unroll
  for (int n = 0; n < 4; ++n) {
    const int col = n0 + wc * 64 + n * 16 + lr;
    const float bv_ = bias[col];
    const int h = col >> 6, d = col & 63;
#pragma unroll
    for (int m = 0; m < 4; ++m) {
      const int row0 = m0 + wr * 64 + m * 16 + lh * 4;
#pragma unroll
      for (int r = 0; r < 4; ++r) {
        const int row = row0 + r;
        const float v = acc[m][n][r] + bv_;
        const int b = row >> 10, s = row & 1023;
        if (z == 0)
          Qo[((size_t)(b * H_N + h) * S_N + s) * D_N + d] = f2b(v);
        else if (z == 1)
          Ko[((size_t)(b * H_N + h) * S_N + s) * D_N + d] = f2b(v);
        else
          Vto[((size_t)(b * H_N + h) * D_N + d) * S_N + s] = f2b(v);
      }
    }
  }
}

// ---------------------------------------------------------------------------
// Output projection, same m97-style staging; fp32 out.
// ---------------------------------------------------------------------------
__global__ __launch_bounds__(256) void out_gemm(
    const bf16_t* __restrict__ A, const bf16_t* __restrict__ W,
    const float* __restrict__ bias, float* __restrict__ Co)
{
  __shared__ bf16_t As[128 * 32];
  __shared__ bf16_t Bs[128 * 32];
  const int tid = threadIdx.x;
  const int m0 = blockIdx.y * 128, n0 = blockIdx.x * 128;
  const int lane = tid & 63, wid = tid >> 6;
  const int wr = wid >> 1, wc = wid & 1;
  const int lr = lane & 15, lh = lane >> 4;
  const int sr = lane >> 2, sc = (lane & 3) * 8;
  f32x4 acc[4][4] = {};
  for (int k0 = 0; k0 < 1024; k0 += 32) {
#pragma unroll
    for (int i = 0; i < 2; ++i) {
      const int br = wid * 32 + i * 16;
      gload_lds16(&A[(size_t)(m0 + br + sr) * 1024 + k0 + sc], &As[br * 32]);
      gload_lds16(&W[(size_t)(n0 + br + sr) * 1024 + k0 + sc], &Bs[br * 32]);
    }
    __syncthreads();
    bf16x8 af[4], bw[4];
#pragma unroll
    for (int m = 0; m < 4; ++m)
      af[m] = *(const bf16x8*)&As[(wr * 64 + m * 16 + lr) * 32 + lh * 8];
#pragma unroll
    for (int n = 0; n < 4; ++n)
      bw[n] = *(const bf16x8*)&Bs[(wc * 64 + n * 16 + lr) * 32 + lh * 8];
#pragma unroll
    for (int m = 0; m < 4; ++m)
#pragma unroll
      for (int n = 0; n < 4; ++n)
        acc[m][n] = MFMA16(af[m], bw[n], acc[m][n], 0, 0, 0);
    __syncthreads();
  }
#pragma unroll
  for (int n = 0; n < 4; ++n) {
    const int col = n0 + wc * 64 + n * 16 + lr;
    const float bv_ = bias[col];
#pragma unroll
    for (int m = 0; m < 4; ++m) {
      const int row0 = m0 + wr * 64 + m * 16 + lh * 4;
#pragma unroll
      for (int r = 0; r < 4; ++r)
        Co[(size_t)(row0 + r) * E_N + col] = acc[m][n][r] + bv_;
    }
  }
}

// ---------------------------------------------------------------------------
// score4: scale + rel_bias (+ mask only if um) for 4 consecutive k.
// ---------------------------------------------------------------------------
static __device__ __forceinline__ f32x4 score4(
    f32x4 acc, int qrow, int kc, const unsigned char* __restrict__ mrow,
    const float* __restrict__ rbh, float rb_lo, float rb_hi, bool um)
{
  const int d0 = kc - qrow;
  float b0, b1, b2, b3;
  if (d0 >= 8) { b0 = b1 = b2 = b3 = rb_hi; }
  else if (d0 <= -11) { b0 = b1 = b2 = b3 = rb_lo; }
  else {
    int dd;
    dd = d0;     dd = dd < -8 ? -8 : (dd > 8 ? 8 : dd); b0 = rbh[dd + 8];
    dd = d0 + 1; dd = dd < -8 ? -8 : (dd > 8 ? 8 : dd); b1 = rbh[dd + 8];
    dd = d0 + 2; dd = dd < -8 ? -8 : (dd > 8 ? 8 : dd); b2 = rbh[dd + 8];
    dd = d0 + 3; dd = dd < -8 ? -8 : (dd > 8 ? 8 : dd); b3 = rbh[dd + 8];
  }
  f32x4 s;
  s[0] = acc[0] * 0.125f + b0;
  s[1] = acc[1] * 0.125f + b1;
  s[2] = acc[2] * 0.125f + b2;
  s[3] = acc[3] * 0.125f + b3;
  if (um) {
    const unsigned int mw = *(const unsigned int*)(mrow + kc);
    const float NEG = -__builtin_inff();
    if (mw & 0xffu)       s[0] = NEG;
    if (mw & 0xff00u)     s[1] = NEG;
    if (mw & 0xff0000u)   s[2] = NEG;
    if (mw & 0xff000000u) s[3] = NEG;
  }
  return s;
}

// ---------------------------------------------------------------------------
// Fused attention (unchanged from r9): LDS-staged K/V, swapped MFMA,
// LDS-transposed coalesced score/attn writes, mask row-flags.
// ---------------------------------------------------------------------------
__global__ __launch_bounds__(256) void fused_attn(
    const bf16_t* __restrict__ Q, const bf16_t* __restrict__ K,
    const bf16_t* __restrict__ Vt,
    const unsigned char* __restrict__ mask, const unsigned char* __restrict__ rowflag,
    const float* __restrict__ rel_bias,
    float* __restrict__ scores, float* __restrict__ attn, bf16_t* __restrict__ ctx)
{
  __shared__ bf16_t Ktile[64 * 64];            // 8KB
  __shared__ bf16_t Vtile[64 * 64];            // 8KB
  __shared__ float S_lds[4][16][68];           // 17KB per-wave transpose tile

  const int bh = blockIdx.y, b = bh >> 4, h = bh & 15;
  const int q0 = blockIdx.x * 64;
  const int tid = threadIdx.x;
  const int w = tid >> 6, lane = tid & 63;
  const int lr = lane & 15, lh = lane >> 4;
  const int qrow = q0 + w * 16 + lr;

  const bf16_t* Qh = Q + (size_t)bh * (S_N * D_N);
  const bf16_t* Kh = K + (size_t)bh * (S_N * D_N);
  const bf16_t* Vh = Vt + (size_t)bh * (D_N * S_N);
  const unsigned char* mrow = mask + (size_t)b * S_N * S_N + (size_t)qrow * S_N;
  float* Sbase = scores + (size_t)bh * S_N * S_N + (size_t)(q0 + w * 16) * S_N;
  float* Abase = attn + (size_t)bh * S_N * S_N + (size_t)(q0 + w * 16) * S_N;
  const float* rbh = rel_bias + h * 17;
  const float rb_lo = rbh[0], rb_hi = rbh[16];
  const float NEG = -__builtin_inff();
  const bool um = rowflag[b * S_N + qrow] != 0;

  const int sg_row0 = tid >> 3, sg_c = tid & 7;
  const int sg_row1 = (tid + 256) >> 3;
  const int sg_s0 = (sg_c ^ (sg_row0 & 7)) * 8;
  const int sg_s1 = (sg_c ^ (sg_row1 & 7)) * 8;

  bf16x8 qa0 = *(const bf16x8*)&Qh[(size_t)qrow * D_N + lh * 8];
  bf16x8 qa1 = *(const bf16x8*)&Qh[(size_t)qrow * D_N + 32 + lh * 8];

  const int ks0 = (lh ^ (lr & 7)) * 8;
  const int ks1 = ((4 + lh) ^ (lr & 7)) * 8;

  // ---- P1: scores + online (max,sum) --------------------------------------
  float mrun = NEG, srun = 0.f;
  for (int kt = 0; kt < 16; ++kt) {
    const int kb = kt * 64;
    __syncthreads();
    *(bf16x8*)&Ktile[sg_row0 * 64 + sg_s0] =
        *(const bf16x8*)&Kh[(size_t)(kb + sg_row0) * D_N + sg_c * 8];
    *(bf16x8*)&Ktile[sg_row1 * 64 + sg_s1] =
        *(const bf16x8*)&Kh[(size_t)(kb + sg_row1) * D_N + sg_c * 8];
    __syncthreads();
#pragma unroll
    for (int t = 0; t < 4; ++t) {
      const int krow = t * 16 + lr;
      bf16x8 ka0 = *(const bf16x8*)&Ktile[krow * 64 + ks0];
      bf16x8 ka1 = *(const bf16x8*)&Ktile[krow * 64 + ks1];
      f32x4 acc = {};
      acc = MFMA16(ka0, qa0, acc, 0, 0, 0);    // D[k][q]
      acc = MFMA16(ka1, qa1, acc, 0, 0, 0);
      const int kc = kb + t * 16 + 4 * lh;
      f32x4 s = score4(acc, qrow, kc, mrow, rbh, rb_lo, rb_hi, um);
      *(f32x4*)&S_lds[w][lr][t * 16 + 4 * lh] = s;
      const float mt = fmaxf(fmaxf(s[0], s[1]), fmaxf(s[2], s[3]));
      const float mn = fmaxf(mrun, mt);
      if (mn > NEG) {
        srun = srun * __expf(mrun - mn)
             + __expf(s[0] - mn) + __expf(s[1] - mn)
             + __expf(s[2] - mn) + __expf(s[3] - mn);
        mrun = mn;
      }
    }
#pragma unroll
    for (int i = 0; i < 4; ++i) {
      const int row = 4 * i + lh;
      f32x4 sv = *(const f32x4*)&S_lds[w][row][lr * 4];
      *(f32x4*)&Sbase[(size_t)row * S_N + kb + lr * 4] = sv;
    }
  }
#pragma unroll
  for (int off = 16; off <= 32; off <<= 1) {
    const float m2 = __shfl_xor(mrun, off);
    const float s2 = __shfl_xor(srun, off);
    const float mn = fmaxf(mrun, m2);
    if (mn > NEG) {
      srun = srun * __expf(mrun - mn) + s2 * __expf(m2 - mn);
      mrun = mn;
    }
  }
  const float M = mrun;
  const float invs = 1.0f / srun;

  // ---- P2: recompute, attn write (coalesced), PV ---------------------------
  f32x4 accp[4] = {};
  for (int kt = 0; kt < 16; ++kt) {
    const int kb = kt * 64;
    __syncthreads();
    *(bf16x8*)&Ktile[sg_row0 * 64 + sg_s0] =
        *(const bf16x8*)&Kh[(size_t)(kb + sg_row0) * D_N + sg_c * 8];
    *(bf16x8*)&Ktile[sg_row1 * 64 + sg_s1] =
        *(const bf16x8*)&Kh[(size_t)(kb + sg_row1) * D_N + sg_c * 8];
    *(bf16x8*)&Vtile[sg_row0 * 64 + sg_s0] =
        *(const bf16x8*)&Vh[(size_t)sg_row0 * S_N + kb + sg_c * 8];
    *(bf16x8*)&Vtile[sg_row1 * 64 + sg_s1] =
        *(const bf16x8*)&Vh[(size_t)sg_row1 * S_N + kb + sg_c * 8];
    __syncthreads();
#pragma unroll
    for (int t = 0; t < 4; ++t) {
      const int krow = t * 16 + lr;
      bf16x8 ka0 = *(const bf16x8*)&Ktile[krow * 64 + ks0];
      bf16x8 ka1 = *(const bf16x8*)&Ktile[krow * 64 + ks1];
      f32x4 acc = {};
      acc = MFMA16(ka0, qa0, acc, 0, 0, 0);
      acc = MFMA16(ka1, qa1, acc, 0, 0, 0);
      const int kc = kb + t * 16 + 4 * lh;
      f32x4 s = score4(acc, qrow, kc, mrow, rbh, rb_lo, rb_hi, um);
      f32x4 p;
#pragma unroll
      for (int j = 0; j < 4; ++j) p[j] = __expf(s[j] - M) * invs;
      *(f32x4*)&S_lds[w][lr][t * 16 + 4 * lh] = p;
    }
#pragma unroll
    for (int i = 0; i < 4; ++i) {
      const int row = 4 * i + lh;
      f32x4 pv = *(const f32x4*)&S_lds[w][row][lr * 4];
      *(f32x4*)&Abase[(size_t)row * S_N + kb + lr * 4] = pv;
    }
#pragma unroll
    for (int ch = 0; ch < 2; ++ch) {
      f32x8 pf = *(const f32x8*)&S_lds[w][lr][ch * 32 + lh * 8];
      bf16x8 pa;
#pragma unroll
      for (int j = 0; j < 8; ++j) pa[j] = f2b(pf[j]);
#pragma unroll
      for (int dt = 0; dt < 4; ++dt) {
        const int drow = dt * 16 + lr;
        bf16x8 vb = *(const bf16x8*)&Vtile[drow * 64 + (((ch * 4 + lh) ^ (lr & 7)) * 8)];
        accp[dt] = MFMA16(pa, vb, accp[dt], 0, 0, 0);    // D[q][d]
      }
    }
  }
#pragma unroll
  for (int dt = 0; dt < 4; ++dt)
#pragma unroll
    for (int r = 0; r < 4; ++r)
      ctx[((size_t)(b * S_N + q0 + w * 16 + 4 * lh + r)) * E_N + h * 64 + dt * 16 + lr] =
          f2b(accp[dt][r]);
}

// ---------------------------------------------------------------------------
extern "C" void kernel_launch(void* const* d_in, const int* in_sizes, int n_in,
                              void* d_out, int out_size, void* d_ws, size_t ws_size,
                              hipStream_t stream) {
  (void)in_sizes; (void)n_in; (void)out_size; (void)ws_size;
  const float* query = (const float*)d_in[0];
  const float* key   = (const float*)d_in[1];
  const float* value = (const float*)d_in[2];
  const unsigned char* mask = (const unsigned char*)d_in[3];
  const float* Wq = (const float*)d_in[4];
  const float* bq = (const float*)d_in[5];
  const float* Wk = (const float*)d_in[6];
  const float* bk = (const float*)d_in[7];
  const float* Wv = (const float*)d_in[8];
  const float* bv = (const float*)d_in[9];
  const float* Wo = (const float*)d_in[10];
  const float* bo = (const float*)d_in[11];
  const float* rel_bias = (const float*)d_in[12];

  float* out_f    = (float*)d_out;                     //  4,194,304 floats
  float* attn_f   = out_f + (size_t)4194304;           // 67,108,864 floats
  float* scores_f = attn_f + (size_t)67108864;         // 67,108,864 floats

  char* ws = (char*)d_ws;                              // ~2GiB; 65MB used
  bf16_t* qbf  = (bf16_t*)(ws);                        // (4096,1024) 8MB
  bf16_t* kbf  = (bf16_t*)(ws + (8ull  << 20));        // 8MB
  bf16_t* vbf  = (bf16_t*)(ws + (16ull << 20));        // 8MB
  bf16_t* Wqb  = (bf16_t*)(ws + (24ull << 20));        // 2MB
  bf16_t* Wkb  = (bf16_t*)(ws + (26ull << 20));        // 2MB
  bf16_t* Wvb  = (bf16_t*)(ws + (28ull << 20));        // 2MB
  bf16_t* Wob  = (bf16_t*)(ws + (30ull << 20));        // 2MB
  bf16_t* Qbf  = (bf16_t*)(ws + (32ull << 20));        // (B,H,S,D) 8MB
  bf16_t* Kbf  = (bf16_t*)(ws + (40ull << 20));        // (B,H,S,D) 8MB
  bf16_t* Vtbf = (bf16_t*)(ws + (48ull << 20));        // (B,H,D,S) 8MB
  bf16_t* CTX  = (bf16_t*)(ws + (56ull << 20));        // (B,S,E)   8MB
  unsigned char* FLAGS = (unsigned char*)(ws + (64ull << 20)); // 4KB

  convert_kernel<<<dim3(8192), dim3(256), 0, stream>>>(
      query, key, value, Wq, Wk, Wv, Wo, qbf, kbf, vbf, Wqb, Wkb, Wvb, Wob);
  mask_rowany<<<dim3(1024), dim3(256), 0, stream>>>(mask, FLAGS);
  qkv_gemm<<<dim3(8, 32, 3), dim3(256), 0, stream>>>(
      qbf, kbf, vbf, Wqb, Wkb, Wvb, bq, bk, bv, Qbf, Kbf, Vtbf);
  fused_attn<<<dim3(16, 64), dim3(256), 0, stream>>>(
      Qbf, Kbf, Vtbf, mask, FLAGS, rel_bias, scores_f, attn_f, CTX);
  out_gemm<<<dim3(8, 32), dim3(256), 0, stream>>>(CTX, Wob, bo, out_f);
}